// Round 13
// baseline (299.146 us; speedup 1.0000x reference)
//
#include <hip/hip_runtime.h>

#define IN_DIM 18
#define XPAD 20     // agg row: 5 float4 slots
#define HID 64
#define EMB 32
#define NGROUP 8    // legacy fallback partitioning
#define PSHIFT 9    // 512 nodes per partition
#define PMAX 200    // LDS arrays sized for <=200 partitions (N<=102400)
#define BCAP 80     // k_part per-tile LDS bin capacity (u32 pairs)
#define TILE 4096
#define SCAP 16896  // k_build LDS pair-staging capacity
#define NPB 16      // nodes per block in k_w12

typedef int vint4 __attribute__((ext_vector_type(4)));
typedef unsigned int u32;

__device__ inline float4 shfl_xor_f4(float4 v, int m) {
    v.x = __shfl_xor(v.x, m);
    v.y = __shfl_xor(v.y, m);
    v.z = __shfl_xor(v.z, m);
    v.w = __shfl_xor(v.w, m);
    return v;
}

// ---------------- init ----------------

__global__ void k_init(int* __restrict__ deg, int* __restrict__ gcnt, int n) {
    int i = blockIdx.x * 256 + threadIdx.x;
    if (i < n) deg[i] = 1;          // legacy path
    if (i < 256) gcnt[i] = 0;
}

// ---------------- bucketing: (dst,src) -> P dst-partition buckets ----------
// pair packed as u32: (src << 9) | (dst & 511)   [requires n < 2^23]

__global__ void k_part(const int* __restrict__ src, const int* __restrict__ dst,
                       int* __restrict__ gcnt, u32* __restrict__ gbuf,
                       int e, int Pp, int cap) {
    __shared__ u32 sbuf[PMAX][BCAP];
    __shared__ int scnt[PMAX];
    __shared__ int sbase[PMAX];
    int tid = threadIdx.x;
    int ntile = (e + TILE - 1) / TILE;
    for (int tile = blockIdx.x; tile < ntile; tile += gridDim.x) {
        for (int p = tid; p < Pp; p += 256) scnt[p] = 0;
        __syncthreads();
#pragma unroll
        for (int r = 0; r < TILE / 1024; ++r) {
            int i = tile * TILE + (r * 256 + tid) * 4;
            if (i + 4 <= e) {
                vint4 s4 = __builtin_nontemporal_load((const vint4*)(src + i));
                vint4 d4 = __builtin_nontemporal_load((const vint4*)(dst + i));
#pragma unroll
                for (int k = 0; k < 4; ++k) {
                    int d = d4[k];
                    int p = d >> PSHIFT;
                    u32 pr = ((u32)s4[k] << PSHIFT) | (u32)(d & 511);
                    int pos = atomicAdd(&scnt[p], 1);
                    if (pos < BCAP) sbuf[p][pos] = pr;
                    else {
                        int gp = atomicAdd(&gcnt[p], 1);
                        __builtin_nontemporal_store(pr, &gbuf[(size_t)p * cap + gp]);
                    }
                }
            } else if (i < e) {
                for (int k = i; k < e; ++k) {
                    int d = dst[k];
                    int p = d >> PSHIFT;
                    u32 pr = ((u32)src[k] << PSHIFT) | (u32)(d & 511);
                    int pos = atomicAdd(&scnt[p], 1);
                    if (pos < BCAP) sbuf[p][pos] = pr;
                    else {
                        int gp = atomicAdd(&gcnt[p], 1);
                        __builtin_nontemporal_store(pr, &gbuf[(size_t)p * cap + gp]);
                    }
                }
            }
        }
        __syncthreads();
        for (int p = tid; p < Pp; p += 256)
            sbase[p] = atomicAdd(&gcnt[p], min(scnt[p], BCAP));
        __syncthreads();
        int wid = tid >> 6, lane = tid & 63;
        for (int p = wid; p < Pp; p += 4) {
            int c = min(scnt[p], BCAP);
            int b = sbase[p];
            for (int k = lane; k < c; k += 64)
                __builtin_nontemporal_store(sbuf[p][k], &gbuf[(size_t)p * cap + b + k]);
        }
        __syncthreads();
    }
}

// ---------------- tiny exclusive scan of bucket counts ----------------

__global__ void k_gscan(const int* __restrict__ gcnt, int* __restrict__ gbase, int Pp) {
    __shared__ int s[256];
    int t = threadIdx.x;
    int v = (t < Pp) ? gcnt[t] : 0;
    s[t] = v;
    __syncthreads();
    for (int off = 1; off < 256; off <<= 1) {
        int u = (t >= off) ? s[t - off] : 0;
        __syncthreads();
        s[t] += u;
        __syncthreads();
    }
    if (t < Pp) gbase[t] = s[t] - v;
}

// ---------------- per-partition build: deg/dis/row_ptr/adj (512 thr) --------

__global__ void k_build(const u32* __restrict__ gbuf, const int* __restrict__ gcnt,
                        const int* __restrict__ gbase, int* __restrict__ deg,
                        float* __restrict__ dis, int* __restrict__ row_ptr,
                        int* __restrict__ adj, int cap, int n) {
    __shared__ u32 spairs[SCAP];
    __shared__ int sdeg[512];
    __shared__ int sexcl[512];
    __shared__ int swp[512];
    __shared__ int sscan[512];
    int p = blockIdx.x;
    int tid = threadIdx.x;
    int lo = p << PSHIFT;
    int nn = min(n - lo, 512);
    int cnt = gcnt[p];
    int base = gbase[p];
    const u32* buf = gbuf + (size_t)p * cap;

    sdeg[tid] = 0;
    int scap = min(cnt, SCAP);
    for (int k = tid; k < scap; k += 512)
        spairs[k] = __builtin_nontemporal_load(&buf[k]);
    __syncthreads();
    for (int k = tid; k < cnt; k += 512) {
        u32 pr = (k < SCAP) ? spairs[k] : __builtin_nontemporal_load(&buf[k]);
        atomicAdd(&sdeg[pr & 511], 1);
    }
    __syncthreads();
    int v = sdeg[tid];
    sscan[tid] = v;
    __syncthreads();
    for (int off = 1; off < 512; off <<= 1) {
        int u = (tid >= off) ? sscan[tid - off] : 0;
        __syncthreads();
        sscan[tid] += u;
        __syncthreads();
    }
    sexcl[tid] = sscan[tid] - v;
    swp[tid] = 0;
    __syncthreads();
    if (tid < nn) {
        int dg = sdeg[tid] + 1;
        deg[lo + tid] = dg;
        dis[lo + tid] = rsqrtf((float)dg);
        row_ptr[lo + tid] = base + sexcl[tid];
    }
    for (int k = tid; k < cnt; k += 512) {
        u32 pr = (k < SCAP) ? spairs[k] : __builtin_nontemporal_load(&buf[k]);
        int dl = pr & 511;
        int slot = sexcl[dl] + atomicAdd(&swp[dl], 1);
        adj[base + slot] = (int)(pr >> PSHIFT);
    }
}

// ---------------- legacy fallback ----------------

__global__ void k_count_part(const int* __restrict__ dst, int* __restrict__ deg,
                             int e, int nrange, int n) {
    int g  = blockIdx.x & (NGROUP - 1);
    int lo = g * nrange;
    int hi = min(n, lo + nrange);
    int bid  = blockIdx.x >> 3;
    int nblk = gridDim.x >> 3;
    int i0   = (bid * 256 + threadIdx.x) * 4;
    int step = nblk * 256 * 4;
    for (int i = i0; i < e; i += step) {
        if (i + 4 <= e) {
            int4 d4 = *(const int4*)(dst + i);
            if (d4.x >= lo && d4.x < hi) atomicAdd(&deg[d4.x], 1);
            if (d4.y >= lo && d4.y < hi) atomicAdd(&deg[d4.y], 1);
            if (d4.z >= lo && d4.z < hi) atomicAdd(&deg[d4.z], 1);
            if (d4.w >= lo && d4.w < hi) atomicAdd(&deg[d4.w], 1);
        } else {
            for (int k = i; k < e; ++k) {
                int d = dst[k];
                if (d >= lo && d < hi) atomicAdd(&deg[d], 1);
            }
        }
    }
}

__global__ void k_dis(const int* __restrict__ deg, float* __restrict__ dis, int n) {
    int i = blockIdx.x * 256 + threadIdx.x;
    if (i < n) dis[i] = rsqrtf((float)deg[i]);
}

__global__ void k_scanA(const int* __restrict__ deg, int* __restrict__ row_ptr,
                        int* __restrict__ blksums, int n) {
    __shared__ int s[1024];
    int tid = threadIdx.x;
    int i = blockIdx.x * 1024 + tid;
    int v = (i < n) ? (deg[i] - 1) : 0;
    s[tid] = v;
    __syncthreads();
    for (int off = 1; off < 1024; off <<= 1) {
        int t = (tid >= off) ? s[tid - off] : 0;
        __syncthreads();
        s[tid] += t;
        __syncthreads();
    }
    if (i < n) row_ptr[i] = s[tid] - v;
    if (tid == 1023) blksums[blockIdx.x] = s[1023];
}

__global__ void k_scanB(const int* __restrict__ blksums, int* __restrict__ blkoffs, int nb) {
    __shared__ int s[1024];
    int tid = threadIdx.x;
    int v = (tid < nb) ? blksums[tid] : 0;
    s[tid] = v;
    __syncthreads();
    for (int off = 1; off < 1024; off <<= 1) {
        int t = (tid >= off) ? s[tid - off] : 0;
        __syncthreads();
        s[tid] += t;
        __syncthreads();
    }
    if (tid < nb) blkoffs[tid] = s[tid] - v;
}

__global__ void k_scanC(int* __restrict__ row_ptr, const int* __restrict__ blkoffs,
                        int* __restrict__ write_ptr, int n) {
    int i = blockIdx.x * 1024 + threadIdx.x;
    if (i < n) {
        int r = row_ptr[i] + blkoffs[blockIdx.x];
        row_ptr[i] = r;
        write_ptr[i] = r;
    }
}

__global__ void k_fill_part(const int* __restrict__ src, const int* __restrict__ dst,
                            int* __restrict__ write_ptr, int* __restrict__ adj,
                            int e, int nrange, int n) {
    int g  = blockIdx.x & (NGROUP - 1);
    int lo = g * nrange;
    int hi = min(n, lo + nrange);
    int bid  = blockIdx.x >> 3;
    int nblk = gridDim.x >> 3;
    int i0   = (bid * 256 + threadIdx.x) * 4;
    int step = nblk * 256 * 4;
    for (int i = i0; i < e; i += step) {
        if (i + 4 <= e) {
            int4 d4 = *(const int4*)(dst + i);
            if (d4.x >= lo && d4.x < hi) { int slot = atomicAdd(&write_ptr[d4.x], 1); adj[slot] = src[i];     }
            if (d4.y >= lo && d4.y < hi) { int slot = atomicAdd(&write_ptr[d4.y], 1); adj[slot] = src[i + 1]; }
            if (d4.z >= lo && d4.z < hi) { int slot = atomicAdd(&write_ptr[d4.z], 1); adj[slot] = src[i + 2]; }
            if (d4.w >= lo && d4.w < hi) { int slot = atomicAdd(&write_ptr[d4.w], 1); adj[slot] = src[i + 3]; }
        } else {
            for (int k = i; k < e; ++k) {
                int d = dst[k];
                if (d >= lo && d < hi) { int slot = atomicAdd(&write_ptr[d], 1); adj[slot] = src[k]; }
            }
        }
    }
}

// ---------------- xn slices: xs0[n][8] dims0-7, xs1[n][8] dims8-15, xs2[n][4] --

__global__ void k_xn(const float* __restrict__ x, const float* __restrict__ dis,
                     float* __restrict__ xs0, float* __restrict__ xs1,
                     float* __restrict__ xs2, int n) {
    int gid = blockIdx.x * 256 + threadIdx.x;
    if (gid >= n * 5) return;
    int i = gid / 5, s = gid - (gid / 5) * 5;
    float dn = dis[i];
    const float* xr = x + (size_t)i * IN_DIM;
    float4 v;
    int k = s * 4;
    v.x = (k + 0 < IN_DIM) ? xr[k + 0] * dn : 0.f;
    v.y = (k + 1 < IN_DIM) ? xr[k + 1] * dn : 0.f;
    v.z = (k + 2 < IN_DIM) ? xr[k + 2] * dn : 0.f;
    v.w = (k + 3 < IN_DIM) ? xr[k + 3] * dn : 0.f;
    if (s < 2)      *(float4*)(xs0 + (size_t)i * 8 + s * 4) = v;
    else if (s < 4) *(float4*)(xs1 + (size_t)i * 8 + (s - 2) * 4) = v;
    else            *(float4*)(xs2 + (size_t)i * 4) = v;
}

// ---------------- slot-pass gather, 2 float4 slots (32B rows, L2-resident) ---
// Wave per node: 32 edge-groups x 2 slots, x2 unroll = 64 gathers in flight.
// Writes agg[node][aggoff .. aggoff+7] = self + sum_neighbors (full degree).

__global__ void k_sp2s(const float* __restrict__ xs, const int* __restrict__ row_ptr,
                       const int* __restrict__ deg, const int* __restrict__ adj,
                       float* __restrict__ agg, int aggoff, int n) {
    int node = blockIdx.x * 4 + (threadIdx.x >> 6);
    if (node >= n) return;
    int lane = threadIdx.x & 63;
    int eg = lane >> 1, sl = lane & 1;
    int beg = row_ptr[node];
    int cnt = deg[node] - 1;
    const int* a = adj + beg;
    float4 acc = make_float4(0.f, 0.f, 0.f, 0.f);
    int base = 0;
    for (; base + 64 <= cnt; base += 64) {
        int j0 = __builtin_nontemporal_load(&a[base + eg]);
        int j1 = __builtin_nontemporal_load(&a[base + 32 + eg]);
        float4 v0 = *(const float4*)(xs + (size_t)j0 * 8 + sl * 4);
        float4 v1 = *(const float4*)(xs + (size_t)j1 * 8 + sl * 4);
        acc.x += v0.x + v1.x; acc.y += v0.y + v1.y;
        acc.z += v0.z + v1.z; acc.w += v0.w + v1.w;
    }
    if (base + eg < cnt) {
        int j = __builtin_nontemporal_load(&a[base + eg]);
        float4 v = *(const float4*)(xs + (size_t)j * 8 + sl * 4);
        acc.x += v.x; acc.y += v.y; acc.z += v.z; acc.w += v.w;
    }
    if (base + 32 + eg < cnt) {
        int j = __builtin_nontemporal_load(&a[base + 32 + eg]);
        float4 v = *(const float4*)(xs + (size_t)j * 8 + sl * 4);
        acc.x += v.x; acc.y += v.y; acc.z += v.z; acc.w += v.w;
    }
    // reduce across 32 edge-groups (sl parity preserved)
    float4 t = shfl_xor_f4(acc, 2);  acc.x += t.x; acc.y += t.y; acc.z += t.z; acc.w += t.w;
    t = shfl_xor_f4(acc, 4);  acc.x += t.x; acc.y += t.y; acc.z += t.z; acc.w += t.w;
    t = shfl_xor_f4(acc, 8);  acc.x += t.x; acc.y += t.y; acc.z += t.z; acc.w += t.w;
    t = shfl_xor_f4(acc, 16); acc.x += t.x; acc.y += t.y; acc.z += t.z; acc.w += t.w;
    t = shfl_xor_f4(acc, 32); acc.x += t.x; acc.y += t.y; acc.z += t.z; acc.w += t.w;
    if (lane < 2) {
        float4 self = *(const float4*)(xs + (size_t)node * 8 + lane * 4);
        acc.x += self.x; acc.y += self.y; acc.z += self.z; acc.w += self.w;
        __builtin_nontemporal_store(acc.x, agg + (size_t)node * XPAD + aggoff + lane * 4 + 0);
        __builtin_nontemporal_store(acc.y, agg + (size_t)node * XPAD + aggoff + lane * 4 + 1);
        __builtin_nontemporal_store(acc.z, agg + (size_t)node * XPAD + aggoff + lane * 4 + 2);
        __builtin_nontemporal_store(acc.w, agg + (size_t)node * XPAD + aggoff + lane * 4 + 3);
    }
}

// ---------------- slot-pass gather, 1 float4 slot (16B rows) ----------------

__global__ void k_sp1s(const float* __restrict__ xs, const int* __restrict__ row_ptr,
                       const int* __restrict__ deg, const int* __restrict__ adj,
                       float* __restrict__ agg, int aggoff, int n) {
    int node = blockIdx.x * 4 + (threadIdx.x >> 6);
    if (node >= n) return;
    int lane = threadIdx.x & 63;
    int beg = row_ptr[node];
    int cnt = deg[node] - 1;
    const int* a = adj + beg;
    float4 acc = make_float4(0.f, 0.f, 0.f, 0.f);
    int base = 0;
    for (; base + 128 <= cnt; base += 128) {
        int j0 = __builtin_nontemporal_load(&a[base + lane]);
        int j1 = __builtin_nontemporal_load(&a[base + 64 + lane]);
        float4 v0 = *(const float4*)(xs + (size_t)j0 * 4);
        float4 v1 = *(const float4*)(xs + (size_t)j1 * 4);
        acc.x += v0.x + v1.x; acc.y += v0.y + v1.y;
        acc.z += v0.z + v1.z; acc.w += v0.w + v1.w;
    }
    if (base + lane < cnt) {
        int j = __builtin_nontemporal_load(&a[base + lane]);
        float4 v = *(const float4*)(xs + (size_t)j * 4);
        acc.x += v.x; acc.y += v.y; acc.z += v.z; acc.w += v.w;
    }
    if (base + 64 + lane < cnt) {
        int j = __builtin_nontemporal_load(&a[base + 64 + lane]);
        float4 v = *(const float4*)(xs + (size_t)j * 4);
        acc.x += v.x; acc.y += v.y; acc.z += v.z; acc.w += v.w;
    }
    for (int m = 1; m <= 32; m <<= 1) {
        float4 t = shfl_xor_f4(acc, m);
        acc.x += t.x; acc.y += t.y; acc.z += t.z; acc.w += t.w;
    }
    if (lane == 0) {
        float4 self = *(const float4*)(xs + (size_t)node * 4);
        acc.x += self.x; acc.y += self.y; acc.z += self.z; acc.w += self.w;
        __builtin_nontemporal_store(acc.x, agg + (size_t)node * XPAD + aggoff + 0);
        __builtin_nontemporal_store(acc.y, agg + (size_t)node * XPAD + aggoff + 1);
        __builtin_nontemporal_store(acc.z, agg + (size_t)node * XPAD + aggoff + 2);
        __builtin_nontemporal_store(acc.w, agg + (size_t)node * XPAD + aggoff + 3);
    }
}

// ---------------- epilogue: agg -> W1+bias+relu -> W2 -> hn2 ----------------

__global__ void k_w12(const float* __restrict__ agg, const float* __restrict__ dis,
                      const float* __restrict__ W1, const float* __restrict__ b1,
                      const float* __restrict__ W2, float* __restrict__ hn2, int n) {
    __shared__ float sw[IN_DIM * HID];
    __shared__ float sw2[HID * EMB];
    __shared__ float sb[HID];
    __shared__ __align__(16) float sagg[4][XPAD];
    __shared__ float sh[4][HID];
    int tid = threadIdx.x;
    for (int t = tid; t < IN_DIM * HID; t += 256) sw[t] = W1[t];
    for (int t = tid; t < HID * EMB; t += 256) sw2[t] = W2[t];
    if (tid < HID) sb[tid] = b1[tid];
    __syncthreads();
    int lane = tid & 63;
    int wv = tid >> 6;
    for (int nd = wv; nd < NPB; nd += 4) {
        int node = blockIdx.x * NPB + nd;
        if (node >= n) break;
        float dn = dis[node];
        if (lane < 5) {
            float4 v = *(const float4*)(agg + (size_t)node * XPAD + lane * 4);
            *(float4*)&sagg[wv][lane * 4] = v;   // same-wave LDS
        }
        float s = 0.f;
#pragma unroll
        for (int k = 0; k < IN_DIM; ++k) s += sagg[wv][k] * sw[k * HID + lane];
        float hv = dn * s + sb[lane];
        sh[wv][lane] = hv > 0.f ? hv : 0.f;
        int g = lane & 31, half = lane >> 5;
        float s2 = 0.f;
#pragma unroll
        for (int k = 0; k < 32; ++k)
            s2 += sh[wv][half * 32 + k] * sw2[(half * 32 + k) * EMB + g];
        s2 += __shfl_xor(s2, 32);
        if (half == 0) hn2[(size_t)node * EMB + g] = dn * s2;
    }
}

// ---------------- layer-2 aggregation (float4 per lane, x3 unroll) ----------

__global__ void k_agg2(const float* __restrict__ hn2, const int* __restrict__ row_ptr,
                       const int* __restrict__ deg, const int* __restrict__ adj,
                       const float* __restrict__ dis, const float* __restrict__ b2,
                       float* __restrict__ z, int n) {
    int node = blockIdx.x * 4 + (threadIdx.x >> 6);
    if (node >= n) return;
    int lane = threadIdx.x & 63;
    int eg = lane >> 3;
    int d4 = lane & 7;
    int beg = row_ptr[node];
    int cnt = deg[node] - 1;
    const int* a = adj + beg;
    float4 acc = make_float4(0.f, 0.f, 0.f, 0.f);
    int base = 0;
    for (; base + 24 <= cnt; base += 24) {
        int j0 = a[base + eg];
        int j1 = a[base + 8 + eg];
        int j2 = a[base + 16 + eg];
        float4 v0 = *(const float4*)(hn2 + (size_t)j0 * EMB + d4 * 4);
        float4 v1 = *(const float4*)(hn2 + (size_t)j1 * EMB + d4 * 4);
        float4 v2 = *(const float4*)(hn2 + (size_t)j2 * EMB + d4 * 4);
        acc.x += v0.x + v1.x + v2.x; acc.y += v0.y + v1.y + v2.y;
        acc.z += v0.z + v1.z + v2.z; acc.w += v0.w + v1.w + v2.w;
    }
    int kk = base + eg;
    if (kk < cnt) {
        float4 v = *(const float4*)(hn2 + (size_t)a[kk] * EMB + d4 * 4);
        acc.x += v.x; acc.y += v.y; acc.z += v.z; acc.w += v.w;
    }
    kk += 8;
    if (kk < cnt) {
        float4 v = *(const float4*)(hn2 + (size_t)a[kk] * EMB + d4 * 4);
        acc.x += v.x; acc.y += v.y; acc.z += v.z; acc.w += v.w;
    }
    kk += 8;
    if (kk < cnt) {
        float4 v = *(const float4*)(hn2 + (size_t)a[kk] * EMB + d4 * 4);
        acc.x += v.x; acc.y += v.y; acc.z += v.z; acc.w += v.w;
    }
    float4 t = shfl_xor_f4(acc, 8);
    acc.x += t.x; acc.y += t.y; acc.z += t.z; acc.w += t.w;
    t = shfl_xor_f4(acc, 16);
    acc.x += t.x; acc.y += t.y; acc.z += t.z; acc.w += t.w;
    t = shfl_xor_f4(acc, 32);
    acc.x += t.x; acc.y += t.y; acc.z += t.z; acc.w += t.w;
    if (eg == 0) {
        float4 self = *(const float4*)(hn2 + (size_t)node * EMB + d4 * 4);
        float4 bb = *(const float4*)(b2 + d4 * 4);
        float dn = dis[node];
        float4 o;
        o.x = dn * (acc.x + self.x) + bb.x;
        o.y = dn * (acc.y + self.y) + bb.y;
        o.z = dn * (acc.z + self.z) + bb.z;
        o.w = dn * (acc.w + self.w) + bb.w;
        *(float4*)(z + (size_t)node * EMB + d4 * 4) = o;
    }
}

// ---------------- pair head ----------------

__global__ void k_head(const float* __restrict__ z, const int* __restrict__ tg,
                       const float* __restrict__ Wo, const float* __restrict__ bo,
                       float* __restrict__ out, int btot) {
    int i = blockIdx.x * 256 + threadIdx.x;
    if (i >= btot) return;
    int t0 = tg[i], t1 = tg[btot + i];
    const float* z0 = z + (size_t)t0 * EMB;
    const float* z1 = z + (size_t)t1 * EMB;
    float acc = 0.f;
#pragma unroll
    for (int g = 0; g < EMB; ++g) acc += z0[g] * z1[g] * Wo[g];
    out[i] = acc + bo[0];
}

// ---------------- launch ----------------

extern "C" void kernel_launch(void* const* d_in, const int* in_sizes, int n_in,
                              void* d_out, int out_size, void* d_ws, size_t ws_size,
                              hipStream_t stream) {
    const float* x  = (const float*)d_in[0];
    const int*   ei = (const int*)d_in[1];
    const int*   tg = (const int*)d_in[2];
    const float* W1 = (const float*)d_in[3];
    const float* b1 = (const float*)d_in[4];
    const float* W2 = (const float*)d_in[5];
    const float* b2 = (const float*)d_in[6];
    const float* Wo = (const float*)d_in[7];
    const float* bo = (const float*)d_in[8];
    float* out = (float*)d_out;

    int n = in_sizes[0] / IN_DIM;
    int e = in_sizes[1] / 2;
    int b = in_sizes[2] / 2;
    const int* src = ei;
    const int* dst = ei + e;

    char* ws = (char*)d_ws;
    size_t off = 0;
    auto alloc = [&](size_t bytes) -> char* {
        char* p = ws + off;
        off += (bytes + 255) & ~(size_t)255;
        return p;
    };
    int*   deg       = (int*)alloc((size_t)n * 4);
    int*   row_ptr   = (int*)alloc((size_t)n * 4);
    int*   write_ptr = (int*)alloc((size_t)n * 4);
    int*   blksums   = (int*)alloc(1024 * 4);
    int*   blkoffs   = (int*)alloc(1024 * 4);
    float* dis       = (float*)alloc((size_t)n * 4);
    int*   adj       = (int*)alloc((size_t)e * 4);
    float* xs0       = (float*)alloc((size_t)n * 8 * 4);     // dims 0-7
    float* xs1       = (float*)alloc((size_t)n * 8 * 4);     // dims 8-15
    float* xs2       = (float*)alloc((size_t)n * 4 * 4);     // dims 16-19
    float* agg       = (float*)alloc((size_t)n * XPAD * 4);  // aggregated input rows
    float* bufA      = (float*)alloc((size_t)n * EMB * 4);   // hn2
    float* bufB      = (float*)alloc((size_t)n * EMB * 4);   // z
    int*   gcnt      = (int*)alloc(1024);
    int*   gbase     = (int*)alloc(1024);

    int Pp = (n + 511) >> PSHIFT;
    int meanb = (Pp > 0) ? (e / Pp) : e;
    int cap = meanb + meanb / 16 + 1024;
    size_t bucket_bytes = (size_t)Pp * cap * 4;   // u32 pairs
    bool use_buckets = (Pp <= PMAX) && (n < (1 << 23)) &&
                       ((off + bucket_bytes + 256) <= ws_size);
    u32* gbuf = (u32*)alloc(bucket_bytes);

    int nb1024 = (n + 1023) / 1024;
    int nrange = (n + NGROUP - 1) / NGROUP;
    int nblk4 = (n + 3) / 4;

    k_init<<<(n + 255) / 256, 256, 0, stream>>>(deg, gcnt, n);

    if (use_buckets) {
        k_part<<<512, 256, 0, stream>>>(src, dst, gcnt, gbuf, e, Pp, cap);
        k_gscan<<<1, 256, 0, stream>>>(gcnt, gbase, Pp);
        k_build<<<Pp, 512, 0, stream>>>(gbuf, gcnt, gbase, deg, dis, row_ptr, adj, cap, n);
    } else {
        k_count_part<<<2048, 256, 0, stream>>>(dst, deg, e, nrange, n);
        k_dis<<<(n + 255) / 256, 256, 0, stream>>>(deg, dis, n);
        k_scanA<<<nb1024, 1024, 0, stream>>>(deg, row_ptr, blksums, n);
        k_scanB<<<1, 1024, 0, stream>>>(blksums, blkoffs, nb1024);
        k_scanC<<<nb1024, 1024, 0, stream>>>(row_ptr, blkoffs, write_ptr, n);
        k_fill_part<<<2048, 256, 0, stream>>>(src, dst, write_ptr, adj, e, nrange, n);
    }

    k_xn<<<((size_t)n * 5 + 255) / 256, 256, 0, stream>>>(x, dis, xs0, xs1, xs2, n);

    // layer 1: three slot-passes (each slice table L2-resident), then epilogue
    k_sp2s<<<nblk4, 256, 0, stream>>>(xs0, row_ptr, deg, adj, agg, 0, n);
    k_sp2s<<<nblk4, 256, 0, stream>>>(xs1, row_ptr, deg, adj, agg, 8, n);
    k_sp1s<<<nblk4, 256, 0, stream>>>(xs2, row_ptr, deg, adj, agg, 16, n);
    k_w12<<<(n + NPB - 1) / NPB, 256, 0, stream>>>(agg, dis, W1, b1, W2, bufA, n);

    k_agg2<<<nblk4, 256, 0, stream>>>(bufA, row_ptr, deg, adj, dis, b2, bufB, n);

    k_head<<<(b + 255) / 256, 256, 0, stream>>>(bufB, tg, Wo, bo, out, b);
}

// Round 14
// 276.675 us; speedup vs baseline: 1.0812x; 1.0812x over previous
//
#include <hip/hip_runtime.h>

#define IN_DIM 18
#define XPAD 20     // 5 float4 slots
#define HID 64
#define EMB 32
#define NGROUP 8    // legacy fallback partitioning
#define PSHIFT 9    // 512 nodes per partition
#define PMAX 200    // LDS arrays sized for <=200 partitions (N<=102400)
#define BCAP 80     // k_part per-tile LDS bin capacity (u32 pairs)
#define TILE 4096
#define SCAP 16896  // k_build LDS pair-staging capacity
#define NPB 16      // nodes per block in k_agg1f

typedef int vint4 __attribute__((ext_vector_type(4)));
typedef unsigned int u32;

__device__ inline float4 shfl_xor_f4(float4 v, int m) {
    v.x = __shfl_xor(v.x, m);
    v.y = __shfl_xor(v.y, m);
    v.z = __shfl_xor(v.z, m);
    v.w = __shfl_xor(v.w, m);
    return v;
}

__device__ inline float4 shfl_f4(float4 v, int srcLane) {
    float4 r;
    r.x = __shfl(v.x, srcLane);
    r.y = __shfl(v.y, srcLane);
    r.z = __shfl(v.z, srcLane);
    r.w = __shfl(v.w, srcLane);
    return r;
}

// ---------------- init ----------------

__global__ void k_init(int* __restrict__ deg, int* __restrict__ gcnt, int n) {
    int i = blockIdx.x * 256 + threadIdx.x;
    if (i < n) deg[i] = 1;          // legacy path
    if (i < 256) gcnt[i] = 0;
}

// ---------------- bucketing: (dst,src) -> P dst-partition buckets ----------
// pair packed as u32: (src << 9) | (dst & 511)   [requires n < 2^23]

__global__ void k_part(const int* __restrict__ src, const int* __restrict__ dst,
                       int* __restrict__ gcnt, u32* __restrict__ gbuf,
                       int e, int Pp, int cap) {
    __shared__ u32 sbuf[PMAX][BCAP];
    __shared__ int scnt[PMAX];
    __shared__ int sbase[PMAX];
    int tid = threadIdx.x;
    int ntile = (e + TILE - 1) / TILE;
    for (int tile = blockIdx.x; tile < ntile; tile += gridDim.x) {
        for (int p = tid; p < Pp; p += 256) scnt[p] = 0;
        __syncthreads();
#pragma unroll
        for (int r = 0; r < TILE / 1024; ++r) {
            int i = tile * TILE + (r * 256 + tid) * 4;
            if (i + 4 <= e) {
                vint4 s4 = __builtin_nontemporal_load((const vint4*)(src + i));
                vint4 d4 = __builtin_nontemporal_load((const vint4*)(dst + i));
#pragma unroll
                for (int k = 0; k < 4; ++k) {
                    int d = d4[k];
                    int p = d >> PSHIFT;
                    u32 pr = ((u32)s4[k] << PSHIFT) | (u32)(d & 511);
                    int pos = atomicAdd(&scnt[p], 1);
                    if (pos < BCAP) sbuf[p][pos] = pr;
                    else {
                        int gp = atomicAdd(&gcnt[p], 1);
                        __builtin_nontemporal_store(pr, &gbuf[(size_t)p * cap + gp]);
                    }
                }
            } else if (i < e) {
                for (int k = i; k < e; ++k) {
                    int d = dst[k];
                    int p = d >> PSHIFT;
                    u32 pr = ((u32)src[k] << PSHIFT) | (u32)(d & 511);
                    int pos = atomicAdd(&scnt[p], 1);
                    if (pos < BCAP) sbuf[p][pos] = pr;
                    else {
                        int gp = atomicAdd(&gcnt[p], 1);
                        __builtin_nontemporal_store(pr, &gbuf[(size_t)p * cap + gp]);
                    }
                }
            }
        }
        __syncthreads();
        for (int p = tid; p < Pp; p += 256)
            sbase[p] = atomicAdd(&gcnt[p], min(scnt[p], BCAP));
        __syncthreads();
        int wid = tid >> 6, lane = tid & 63;
        for (int p = wid; p < Pp; p += 4) {
            int c = min(scnt[p], BCAP);
            int b = sbase[p];
            for (int k = lane; k < c; k += 64)
                __builtin_nontemporal_store(sbuf[p][k], &gbuf[(size_t)p * cap + b + k]);
        }
        __syncthreads();
    }
}

// ---------------- tiny exclusive scan of bucket counts ----------------

__global__ void k_gscan(const int* __restrict__ gcnt, int* __restrict__ gbase, int Pp) {
    __shared__ int s[256];
    int t = threadIdx.x;
    int v = (t < Pp) ? gcnt[t] : 0;
    s[t] = v;
    __syncthreads();
    for (int off = 1; off < 256; off <<= 1) {
        int u = (t >= off) ? s[t - off] : 0;
        __syncthreads();
        s[t] += u;
        __syncthreads();
    }
    if (t < Pp) gbase[t] = s[t] - v;
}

// ---------------- per-partition build: deg/dis/row_ptr/adj (512 thr) --------

__global__ void k_build(const u32* __restrict__ gbuf, const int* __restrict__ gcnt,
                        const int* __restrict__ gbase, int* __restrict__ deg,
                        float* __restrict__ dis, int* __restrict__ row_ptr,
                        int* __restrict__ adj, int cap, int n) {
    __shared__ u32 spairs[SCAP];
    __shared__ int sdeg[512];
    __shared__ int sexcl[512];
    __shared__ int swp[512];
    __shared__ int sscan[512];
    int p = blockIdx.x;
    int tid = threadIdx.x;
    int lo = p << PSHIFT;
    int nn = min(n - lo, 512);
    int cnt = gcnt[p];
    int base = gbase[p];
    const u32* buf = gbuf + (size_t)p * cap;

    sdeg[tid] = 0;
    int scap = min(cnt, SCAP);
    for (int k = tid; k < scap; k += 512)
        spairs[k] = __builtin_nontemporal_load(&buf[k]);
    __syncthreads();
    for (int k = tid; k < cnt; k += 512) {
        u32 pr = (k < SCAP) ? spairs[k] : __builtin_nontemporal_load(&buf[k]);
        atomicAdd(&sdeg[pr & 511], 1);
    }
    __syncthreads();
    int v = sdeg[tid];
    sscan[tid] = v;
    __syncthreads();
    for (int off = 1; off < 512; off <<= 1) {
        int u = (tid >= off) ? sscan[tid - off] : 0;
        __syncthreads();
        sscan[tid] += u;
        __syncthreads();
    }
    sexcl[tid] = sscan[tid] - v;
    swp[tid] = 0;
    __syncthreads();
    if (tid < nn) {
        int dg = sdeg[tid] + 1;
        deg[lo + tid] = dg;
        dis[lo + tid] = rsqrtf((float)dg);
        row_ptr[lo + tid] = base + sexcl[tid];
    }
    for (int k = tid; k < cnt; k += 512) {
        u32 pr = (k < SCAP) ? spairs[k] : __builtin_nontemporal_load(&buf[k]);
        int dl = pr & 511;
        int slot = sexcl[dl] + atomicAdd(&swp[dl], 1);
        adj[base + slot] = (int)(pr >> PSHIFT);
    }
}

// ---------------- legacy fallback ----------------

__global__ void k_count_part(const int* __restrict__ dst, int* __restrict__ deg,
                             int e, int nrange, int n) {
    int g  = blockIdx.x & (NGROUP - 1);
    int lo = g * nrange;
    int hi = min(n, lo + nrange);
    int bid  = blockIdx.x >> 3;
    int nblk = gridDim.x >> 3;
    int i0   = (bid * 256 + threadIdx.x) * 4;
    int step = nblk * 256 * 4;
    for (int i = i0; i < e; i += step) {
        if (i + 4 <= e) {
            int4 d4 = *(const int4*)(dst + i);
            if (d4.x >= lo && d4.x < hi) atomicAdd(&deg[d4.x], 1);
            if (d4.y >= lo && d4.y < hi) atomicAdd(&deg[d4.y], 1);
            if (d4.z >= lo && d4.z < hi) atomicAdd(&deg[d4.z], 1);
            if (d4.w >= lo && d4.w < hi) atomicAdd(&deg[d4.w], 1);
        } else {
            for (int k = i; k < e; ++k) {
                int d = dst[k];
                if (d >= lo && d < hi) atomicAdd(&deg[d], 1);
            }
        }
    }
}

__global__ void k_dis(const int* __restrict__ deg, float* __restrict__ dis, int n) {
    int i = blockIdx.x * 256 + threadIdx.x;
    if (i < n) dis[i] = rsqrtf((float)deg[i]);
}

__global__ void k_scanA(const int* __restrict__ deg, int* __restrict__ row_ptr,
                        int* __restrict__ blksums, int n) {
    __shared__ int s[1024];
    int tid = threadIdx.x;
    int i = blockIdx.x * 1024 + tid;
    int v = (i < n) ? (deg[i] - 1) : 0;
    s[tid] = v;
    __syncthreads();
    for (int off = 1; off < 1024; off <<= 1) {
        int t = (tid >= off) ? s[tid - off] : 0;
        __syncthreads();
        s[tid] += t;
        __syncthreads();
    }
    if (i < n) row_ptr[i] = s[tid] - v;
    if (tid == 1023) blksums[blockIdx.x] = s[1023];
}

__global__ void k_scanB(const int* __restrict__ blksums, int* __restrict__ blkoffs, int nb) {
    __shared__ int s[1024];
    int tid = threadIdx.x;
    int v = (tid < nb) ? blksums[tid] : 0;
    s[tid] = v;
    __syncthreads();
    for (int off = 1; off < 1024; off <<= 1) {
        int t = (tid >= off) ? s[tid - off] : 0;
        __syncthreads();
        s[tid] += t;
        __syncthreads();
    }
    if (tid < nb) blkoffs[tid] = s[tid] - v;
}

__global__ void k_scanC(int* __restrict__ row_ptr, const int* __restrict__ blkoffs,
                        int* __restrict__ write_ptr, int n) {
    int i = blockIdx.x * 1024 + threadIdx.x;
    if (i < n) {
        int r = row_ptr[i] + blkoffs[blockIdx.x];
        row_ptr[i] = r;
        write_ptr[i] = r;
    }
}

__global__ void k_fill_part(const int* __restrict__ src, const int* __restrict__ dst,
                            int* __restrict__ write_ptr, int* __restrict__ adj,
                            int e, int nrange, int n) {
    int g  = blockIdx.x & (NGROUP - 1);
    int lo = g * nrange;
    int hi = min(n, lo + nrange);
    int bid  = blockIdx.x >> 3;
    int nblk = gridDim.x >> 3;
    int i0   = (bid * 256 + threadIdx.x) * 4;
    int step = nblk * 256 * 4;
    for (int i = i0; i < e; i += step) {
        if (i + 4 <= e) {
            int4 d4 = *(const int4*)(dst + i);
            if (d4.x >= lo && d4.x < hi) { int slot = atomicAdd(&write_ptr[d4.x], 1); adj[slot] = src[i];     }
            if (d4.y >= lo && d4.y < hi) { int slot = atomicAdd(&write_ptr[d4.y], 1); adj[slot] = src[i + 1]; }
            if (d4.z >= lo && d4.z < hi) { int slot = atomicAdd(&write_ptr[d4.z], 1); adj[slot] = src[i + 2]; }
            if (d4.w >= lo && d4.w < hi) { int slot = atomicAdd(&write_ptr[d4.w], 1); adj[slot] = src[i + 3]; }
        } else {
            for (int k = i; k < e; ++k) {
                int d = dst[k];
                if (d >= lo && d < hi) { int slot = atomicAdd(&write_ptr[d], 1); adj[slot] = src[k]; }
            }
        }
    }
}

// ---------------- xn = x * dis, padded to 20 floats ----------------

__global__ void k_xn(const float* __restrict__ x, const float* __restrict__ dis,
                     float* __restrict__ xn, int n) {
    int gid = blockIdx.x * 256 + threadIdx.x;
    if (gid >= n * 5) return;
    int i = gid / 5, s = gid - (gid / 5) * 5;
    float dn = dis[i];
    const float* xr = x + (size_t)i * IN_DIM;
    float4 v;
    int k = s * 4;
    v.x = (k + 0 < IN_DIM) ? xr[k + 0] * dn : 0.f;
    v.y = (k + 1 < IN_DIM) ? xr[k + 1] * dn : 0.f;
    v.z = (k + 2 < IN_DIM) ? xr[k + 2] * dn : 0.f;
    v.w = (k + 3 < IN_DIM) ? xr[k + 3] * dn : 0.f;
    *(float4*)(xn + (size_t)i * XPAD + k) = v;
}

// ---------------- fused layer 1+2a: DUAL-node gather + W1 + relu + W2 -------
// 4 waves x (2 sequential pairs of 2 parallel nodes) = 16 nodes/block.
// Fused predicated loop issues both nodes' gather streams -> 48 in flight.

__global__ void k_agg1f(const float* __restrict__ xn, const int* __restrict__ row_ptr,
                        const int* __restrict__ deg, const int* __restrict__ adj,
                        const float* __restrict__ dis, const float* __restrict__ W1,
                        const float* __restrict__ b1, const float* __restrict__ W2,
                        float* __restrict__ hn2, int n) {
    __shared__ float sw[IN_DIM * HID];
    __shared__ float sw2[HID * EMB];
    __shared__ float sb[HID];
    __shared__ __align__(16) float sagg[4][XPAD];
    __shared__ float sh[4][HID];
    int tid = threadIdx.x;
    for (int t = tid; t < IN_DIM * HID; t += 256) sw[t] = W1[t];
    for (int t = tid; t < HID * EMB; t += 256) sw2[t] = W2[t];
    if (tid < HID) sb[tid] = b1[tid];
    __syncthreads();
    int lane = tid & 63;
    int wv = tid >> 6;
    int eg = lane / 5;               // 0..12 (lanes 60-63 inactive)
    int sl = lane - eg * 5;          // float4 slot 0..4
    bool act = eg < 12;

    for (int pr = 0; pr < 2; ++pr) {
        int node0 = blockIdx.x * NPB + wv * 4 + pr * 2;
        int node1 = node0 + 1;
        if (node0 >= n) break;
        bool has1 = node1 < n;
        int c0 = deg[node0] - 1;
        int c1 = has1 ? (deg[node1] - 1) : 0;
        const int* a0 = adj + row_ptr[node0];
        const int* a1 = has1 ? (adj + row_ptr[node1]) : a0;
        int cmax = max(c0, c1);
        float4 acc0 = make_float4(0.f, 0.f, 0.f, 0.f);
        float4 acc1 = make_float4(0.f, 0.f, 0.f, 0.f);
        for (int base = 0; base < cmax; base += 24) {
            if (act) {
                int i0 = base + eg, i1 = base + 12 + eg;
                if (i0 < c0) {
                    float4 v = *(const float4*)(xn + (size_t)a0[i0] * XPAD + sl * 4);
                    acc0.x += v.x; acc0.y += v.y; acc0.z += v.z; acc0.w += v.w;
                }
                if (i1 < c0) {
                    float4 v = *(const float4*)(xn + (size_t)a0[i1] * XPAD + sl * 4);
                    acc0.x += v.x; acc0.y += v.y; acc0.z += v.z; acc0.w += v.w;
                }
                if (i0 < c1) {
                    float4 v = *(const float4*)(xn + (size_t)a1[i0] * XPAD + sl * 4);
                    acc1.x += v.x; acc1.y += v.y; acc1.z += v.z; acc1.w += v.w;
                }
                if (i1 < c1) {
                    float4 v = *(const float4*)(xn + (size_t)a1[i1] * XPAD + sl * 4);
                    acc1.x += v.x; acc1.y += v.y; acc1.z += v.z; acc1.w += v.w;
                }
            }
        }
        // reduce both accs: 12 groups -> group 0
        float4 t;
        t = shfl_f4(acc0, lane + 30); if (lane < 30) { acc0.x += t.x; acc0.y += t.y; acc0.z += t.z; acc0.w += t.w; }
        t = shfl_f4(acc1, lane + 30); if (lane < 30) { acc1.x += t.x; acc1.y += t.y; acc1.z += t.z; acc1.w += t.w; }
        t = shfl_f4(acc0, lane + 15); if (lane < 15) { acc0.x += t.x; acc0.y += t.y; acc0.z += t.z; acc0.w += t.w; }
        t = shfl_f4(acc1, lane + 15); if (lane < 15) { acc1.x += t.x; acc1.y += t.y; acc1.z += t.z; acc1.w += t.w; }
        t = shfl_f4(acc0, lane + 10); if (lane < 5) { acc0.x += t.x; acc0.y += t.y; acc0.z += t.z; acc0.w += t.w; }
        t = shfl_f4(acc1, lane + 10); if (lane < 5) { acc1.x += t.x; acc1.y += t.y; acc1.z += t.z; acc1.w += t.w; }
        t = shfl_f4(acc0, lane + 5);  if (lane < 5) { acc0.x += t.x; acc0.y += t.y; acc0.z += t.z; acc0.w += t.w; }
        t = shfl_f4(acc1, lane + 5);  if (lane < 5) { acc1.x += t.x; acc1.y += t.y; acc1.z += t.z; acc1.w += t.w; }

        for (int which = 0; which < 2; ++which) {
            int node = which ? node1 : node0;
            if (which && !has1) break;
            float4 acc = which ? acc1 : acc0;
            float dn = dis[node];
            if (lane < 5) {
                float4 s4v = *(const float4*)(xn + (size_t)node * XPAD + lane * 4);
                acc.x += s4v.x; acc.y += s4v.y; acc.z += s4v.z; acc.w += s4v.w;
                *(float4*)&sagg[wv][lane * 4] = acc;   // same-wave LDS
            }
            float s = 0.f;
#pragma unroll
            for (int k = 0; k < IN_DIM; ++k) s += sagg[wv][k] * sw[k * HID + lane];
            float hv = dn * s + sb[lane];
            sh[wv][lane] = hv > 0.f ? hv : 0.f;
            int g = lane & 31, half = lane >> 5;
            float s2 = 0.f;
#pragma unroll
            for (int k = 0; k < 32; ++k)
                s2 += sh[wv][half * 32 + k] * sw2[(half * 32 + k) * EMB + g];
            s2 += __shfl_xor(s2, 32);
            if (half == 0) hn2[(size_t)node * EMB + g] = dn * s2;
        }
    }
}

// ---------------- layer-2 aggregation: DUAL-node, predicated ----------------
// 4 waves x 2 parallel nodes = 8 nodes/block; 32 gathers in flight per wave.

__global__ void k_agg2(const float* __restrict__ hn2, const int* __restrict__ row_ptr,
                       const int* __restrict__ deg, const int* __restrict__ adj,
                       const float* __restrict__ dis, const float* __restrict__ b2,
                       float* __restrict__ z, int n) {
    int wv = threadIdx.x >> 6;
    int lane = threadIdx.x & 63;
    int node0 = blockIdx.x * 8 + wv * 2;
    int node1 = node0 + 1;
    if (node0 >= n) return;
    bool has1 = node1 < n;
    int eg = lane >> 3;
    int d4 = lane & 7;
    int c0 = deg[node0] - 1;
    int c1 = has1 ? (deg[node1] - 1) : 0;
    const int* a0 = adj + row_ptr[node0];
    const int* a1 = has1 ? (adj + row_ptr[node1]) : a0;
    int cmax = max(c0, c1);
    float4 acc0 = make_float4(0.f, 0.f, 0.f, 0.f);
    float4 acc1 = make_float4(0.f, 0.f, 0.f, 0.f);
    for (int base = 0; base < cmax; base += 16) {
        int i0 = base + eg, i1 = base + 8 + eg;
        if (i0 < c0) {
            float4 v = *(const float4*)(hn2 + (size_t)a0[i0] * EMB + d4 * 4);
            acc0.x += v.x; acc0.y += v.y; acc0.z += v.z; acc0.w += v.w;
        }
        if (i1 < c0) {
            float4 v = *(const float4*)(hn2 + (size_t)a0[i1] * EMB + d4 * 4);
            acc0.x += v.x; acc0.y += v.y; acc0.z += v.z; acc0.w += v.w;
        }
        if (i0 < c1) {
            float4 v = *(const float4*)(hn2 + (size_t)a1[i0] * EMB + d4 * 4);
            acc1.x += v.x; acc1.y += v.y; acc1.z += v.z; acc1.w += v.w;
        }
        if (i1 < c1) {
            float4 v = *(const float4*)(hn2 + (size_t)a1[i1] * EMB + d4 * 4);
            acc1.x += v.x; acc1.y += v.y; acc1.z += v.z; acc1.w += v.w;
        }
    }
    float4 t;
    t = shfl_xor_f4(acc0, 8);  acc0.x += t.x; acc0.y += t.y; acc0.z += t.z; acc0.w += t.w;
    t = shfl_xor_f4(acc1, 8);  acc1.x += t.x; acc1.y += t.y; acc1.z += t.z; acc1.w += t.w;
    t = shfl_xor_f4(acc0, 16); acc0.x += t.x; acc0.y += t.y; acc0.z += t.z; acc0.w += t.w;
    t = shfl_xor_f4(acc1, 16); acc1.x += t.x; acc1.y += t.y; acc1.z += t.z; acc1.w += t.w;
    t = shfl_xor_f4(acc0, 32); acc0.x += t.x; acc0.y += t.y; acc0.z += t.z; acc0.w += t.w;
    t = shfl_xor_f4(acc1, 32); acc1.x += t.x; acc1.y += t.y; acc1.z += t.z; acc1.w += t.w;
    if (eg == 0) {
        {
            float4 self = *(const float4*)(hn2 + (size_t)node0 * EMB + d4 * 4);
            float4 bb = *(const float4*)(b2 + d4 * 4);
            float dn = dis[node0];
            float4 o;
            o.x = dn * (acc0.x + self.x) + bb.x;
            o.y = dn * (acc0.y + self.y) + bb.y;
            o.z = dn * (acc0.z + self.z) + bb.z;
            o.w = dn * (acc0.w + self.w) + bb.w;
            *(float4*)(z + (size_t)node0 * EMB + d4 * 4) = o;
        }
        if (has1) {
            float4 self = *(const float4*)(hn2 + (size_t)node1 * EMB + d4 * 4);
            float4 bb = *(const float4*)(b2 + d4 * 4);
            float dn = dis[node1];
            float4 o;
            o.x = dn * (acc1.x + self.x) + bb.x;
            o.y = dn * (acc1.y + self.y) + bb.y;
            o.z = dn * (acc1.z + self.z) + bb.z;
            o.w = dn * (acc1.w + self.w) + bb.w;
            *(float4*)(z + (size_t)node1 * EMB + d4 * 4) = o;
        }
    }
}

// ---------------- pair head ----------------

__global__ void k_head(const float* __restrict__ z, const int* __restrict__ tg,
                       const float* __restrict__ Wo, const float* __restrict__ bo,
                       float* __restrict__ out, int btot) {
    int i = blockIdx.x * 256 + threadIdx.x;
    if (i >= btot) return;
    int t0 = tg[i], t1 = tg[btot + i];
    const float* z0 = z + (size_t)t0 * EMB;
    const float* z1 = z + (size_t)t1 * EMB;
    float acc = 0.f;
#pragma unroll
    for (int g = 0; g < EMB; ++g) acc += z0[g] * z1[g] * Wo[g];
    out[i] = acc + bo[0];
}

// ---------------- launch ----------------

extern "C" void kernel_launch(void* const* d_in, const int* in_sizes, int n_in,
                              void* d_out, int out_size, void* d_ws, size_t ws_size,
                              hipStream_t stream) {
    const float* x  = (const float*)d_in[0];
    const int*   ei = (const int*)d_in[1];
    const int*   tg = (const int*)d_in[2];
    const float* W1 = (const float*)d_in[3];
    const float* b1 = (const float*)d_in[4];
    const float* W2 = (const float*)d_in[5];
    const float* b2 = (const float*)d_in[6];
    const float* Wo = (const float*)d_in[7];
    const float* bo = (const float*)d_in[8];
    float* out = (float*)d_out;

    int n = in_sizes[0] / IN_DIM;
    int e = in_sizes[1] / 2;
    int b = in_sizes[2] / 2;
    const int* src = ei;
    const int* dst = ei + e;

    char* ws = (char*)d_ws;
    size_t off = 0;
    auto alloc = [&](size_t bytes) -> char* {
        char* p = ws + off;
        off += (bytes + 255) & ~(size_t)255;
        return p;
    };
    int*   deg       = (int*)alloc((size_t)n * 4);
    int*   row_ptr   = (int*)alloc((size_t)n * 4);
    int*   write_ptr = (int*)alloc((size_t)n * 4);
    int*   blksums   = (int*)alloc(1024 * 4);
    int*   blkoffs   = (int*)alloc(1024 * 4);
    float* dis       = (float*)alloc((size_t)n * 4);
    int*   adj       = (int*)alloc((size_t)e * 4);
    float* xn        = (float*)alloc((size_t)n * XPAD * 4);
    float* bufA      = (float*)alloc((size_t)n * EMB * 4);   // hn2
    float* bufB      = (float*)alloc((size_t)n * EMB * 4);   // z
    int*   gcnt      = (int*)alloc(1024);
    int*   gbase     = (int*)alloc(1024);

    int Pp = (n + 511) >> PSHIFT;
    int meanb = (Pp > 0) ? (e / Pp) : e;
    int cap = meanb + meanb / 16 + 1024;
    size_t bucket_bytes = (size_t)Pp * cap * 4;   // u32 pairs
    bool use_buckets = (Pp <= PMAX) && (n < (1 << 23)) &&
                       ((off + bucket_bytes + 256) <= ws_size);
    u32* gbuf = (u32*)alloc(bucket_bytes);

    int nb1024 = (n + 1023) / 1024;
    int nrange = (n + NGROUP - 1) / NGROUP;

    k_init<<<(n + 255) / 256, 256, 0, stream>>>(deg, gcnt, n);

    if (use_buckets) {
        k_part<<<512, 256, 0, stream>>>(src, dst, gcnt, gbuf, e, Pp, cap);
        k_gscan<<<1, 256, 0, stream>>>(gcnt, gbase, Pp);
        k_build<<<Pp, 512, 0, stream>>>(gbuf, gcnt, gbase, deg, dis, row_ptr, adj, cap, n);
    } else {
        k_count_part<<<2048, 256, 0, stream>>>(dst, deg, e, nrange, n);
        k_dis<<<(n + 255) / 256, 256, 0, stream>>>(deg, dis, n);
        k_scanA<<<nb1024, 1024, 0, stream>>>(deg, row_ptr, blksums, n);
        k_scanB<<<1, 1024, 0, stream>>>(blksums, blkoffs, nb1024);
        k_scanC<<<nb1024, 1024, 0, stream>>>(row_ptr, blkoffs, write_ptr, n);
        k_fill_part<<<2048, 256, 0, stream>>>(src, dst, write_ptr, adj, e, nrange, n);
    }

    k_xn<<<((size_t)n * 5 + 255) / 256, 256, 0, stream>>>(x, dis, xn, n);
    k_agg1f<<<(n + NPB - 1) / NPB, 256, 0, stream>>>(xn, row_ptr, deg, adj, dis, W1, b1, W2, bufA, n);
    k_agg2<<<(n + 7) / 8, 256, 0, stream>>>(bufA, row_ptr, deg, adj, dis, b2, bufB, n);

    k_head<<<(b + 255) / 256, 256, 0, stream>>>(bufB, tg, Wo, bo, out, b);
}

// Round 15
// 251.227 us; speedup vs baseline: 1.1907x; 1.1013x over previous
//
#include <hip/hip_runtime.h>

#define IN_DIM 18
#define XPAD 20     // 5 float4 slots
#define HID 64
#define EMB 32
#define NGROUP 8    // legacy fallback partitioning
#define PSHIFT 9    // 512 nodes per partition
#define PMAX 200    // <=200 partitions (N<=102400)
#define BCAP 80     // k_part per-tile LDS bin capacity (u32 pairs)
#define TILE 4096
#define SCAP 16896  // k_build LDS pair-staging capacity

typedef int vint4 __attribute__((ext_vector_type(4)));
typedef unsigned int u32;

__device__ inline float4 shfl_f4(float4 v, int srcLane) {
    float4 r;
    r.x = __shfl(v.x, srcLane);
    r.y = __shfl(v.y, srcLane);
    r.z = __shfl(v.z, srcLane);
    r.w = __shfl(v.w, srcLane);
    return r;
}

__device__ inline float4 shfl_xor_f4(float4 v, int m) {
    v.x = __shfl_xor(v.x, m);
    v.y = __shfl_xor(v.y, m);
    v.z = __shfl_xor(v.z, m);
    v.w = __shfl_xor(v.w, m);
    return v;
}

// ---------------- init ----------------

__global__ void k_zero(int* __restrict__ gcnt) {
    gcnt[threadIdx.x] = 0;
}

__global__ void k_init(int* __restrict__ deg, int* __restrict__ gcnt, int n) {
    int i = blockIdx.x * 256 + threadIdx.x;
    if (i < n) deg[i] = 1;          // legacy path
    if (i < 256) gcnt[i] = 0;
}

// ---------------- bucketing: (dst,src) -> P dst-partition buckets ----------
// pair packed as u32: (src << 9) | (dst & 511)   [requires n < 2^23]

__global__ void k_part(const int* __restrict__ src, const int* __restrict__ dst,
                       int* __restrict__ gcnt, u32* __restrict__ gbuf,
                       int e, int Pp, int cap) {
    __shared__ u32 sbuf[PMAX][BCAP];
    __shared__ int scnt[PMAX];
    __shared__ int sbase[PMAX];
    int tid = threadIdx.x;
    int ntile = (e + TILE - 1) / TILE;
    for (int tile = blockIdx.x; tile < ntile; tile += gridDim.x) {
        for (int p = tid; p < Pp; p += 256) scnt[p] = 0;
        __syncthreads();
#pragma unroll
        for (int r = 0; r < TILE / 1024; ++r) {
            int i = tile * TILE + (r * 256 + tid) * 4;
            if (i + 4 <= e) {
                vint4 s4 = __builtin_nontemporal_load((const vint4*)(src + i));
                vint4 d4 = __builtin_nontemporal_load((const vint4*)(dst + i));
#pragma unroll
                for (int k = 0; k < 4; ++k) {
                    int d = d4[k];
                    int p = d >> PSHIFT;
                    u32 pr = ((u32)s4[k] << PSHIFT) | (u32)(d & 511);
                    int pos = atomicAdd(&scnt[p], 1);
                    if (pos < BCAP) sbuf[p][pos] = pr;
                    else {
                        int gp = atomicAdd(&gcnt[p], 1);
                        __builtin_nontemporal_store(pr, &gbuf[(size_t)p * cap + gp]);
                    }
                }
            } else if (i < e) {
                for (int k = i; k < e; ++k) {
                    int d = dst[k];
                    int p = d >> PSHIFT;
                    u32 pr = ((u32)src[k] << PSHIFT) | (u32)(d & 511);
                    int pos = atomicAdd(&scnt[p], 1);
                    if (pos < BCAP) sbuf[p][pos] = pr;
                    else {
                        int gp = atomicAdd(&gcnt[p], 1);
                        __builtin_nontemporal_store(pr, &gbuf[(size_t)p * cap + gp]);
                    }
                }
            }
        }
        __syncthreads();
        for (int p = tid; p < Pp; p += 256)
            sbase[p] = atomicAdd(&gcnt[p], min(scnt[p], BCAP));
        __syncthreads();
        int wid = tid >> 6, lane = tid & 63;
        for (int p = wid; p < Pp; p += 4) {
            int c = min(scnt[p], BCAP);
            int b = sbase[p];
            for (int k = lane; k < c; k += 64)
                __builtin_nontemporal_store(sbuf[p][k], &gbuf[(size_t)p * cap + b + k]);
        }
        __syncthreads();
    }
}

// ---------------- per-partition build (512 thr) with inline gcnt scan --------

__global__ void k_build(const u32* __restrict__ gbuf, const int* __restrict__ gcnt,
                        int* __restrict__ deg, float* __restrict__ dis,
                        int* __restrict__ row_ptr, int* __restrict__ adj,
                        int cap, int n, int Pp) {
    __shared__ u32 spairs[SCAP];
    __shared__ int sdeg[512];
    __shared__ int sexcl[512];
    __shared__ int swp[512];
    __shared__ int sscan[512];
    int p = blockIdx.x;
    int tid = threadIdx.x;
    int lo = p << PSHIFT;
    int nn = min(n - lo, 512);
    int cnt = gcnt[p];
    const u32* buf = gbuf + (size_t)p * cap;

    // inline exclusive prefix of gcnt[0..p) -> base (replaces k_gscan launch)
    if (tid < 256) sscan[tid] = (tid < Pp) ? gcnt[tid] : 0;
    __syncthreads();
    for (int off = 1; off < 256; off <<= 1) {
        int u = 0;
        if (tid < 256 && tid >= off) u = sscan[tid - off];
        __syncthreads();
        if (tid < 256) sscan[tid] += u;
        __syncthreads();
    }
    int base = sscan[p] - cnt;
    __syncthreads();

    sdeg[tid] = 0;
    int scap = min(cnt, SCAP);
    for (int k = tid; k < scap; k += 512)
        spairs[k] = __builtin_nontemporal_load(&buf[k]);
    __syncthreads();
    for (int k = tid; k < cnt; k += 512) {
        u32 pr = (k < SCAP) ? spairs[k] : __builtin_nontemporal_load(&buf[k]);
        atomicAdd(&sdeg[pr & 511], 1);
    }
    __syncthreads();
    int v = sdeg[tid];
    sscan[tid] = v;
    __syncthreads();
    for (int off = 1; off < 512; off <<= 1) {
        int u = (tid >= off) ? sscan[tid - off] : 0;
        __syncthreads();
        sscan[tid] += u;
        __syncthreads();
    }
    sexcl[tid] = sscan[tid] - v;
    swp[tid] = 0;
    __syncthreads();
    if (tid < nn) {
        int dg = sdeg[tid] + 1;
        deg[lo + tid] = dg;
        dis[lo + tid] = rsqrtf((float)dg);
        row_ptr[lo + tid] = base + sexcl[tid];
    }
    for (int k = tid; k < cnt; k += 512) {
        u32 pr = (k < SCAP) ? spairs[k] : __builtin_nontemporal_load(&buf[k]);
        int dl = pr & 511;
        int slot = sexcl[dl] + atomicAdd(&swp[dl], 1);
        adj[base + slot] = (int)(pr >> PSHIFT);
    }
}

// ---------------- legacy fallback ----------------

__global__ void k_count_part(const int* __restrict__ dst, int* __restrict__ deg,
                             int e, int nrange, int n) {
    int g  = blockIdx.x & (NGROUP - 1);
    int lo = g * nrange;
    int hi = min(n, lo + nrange);
    int bid  = blockIdx.x >> 3;
    int nblk = gridDim.x >> 3;
    int i0   = (bid * 256 + threadIdx.x) * 4;
    int step = nblk * 256 * 4;
    for (int i = i0; i < e; i += step) {
        if (i + 4 <= e) {
            int4 d4 = *(const int4*)(dst + i);
            if (d4.x >= lo && d4.x < hi) atomicAdd(&deg[d4.x], 1);
            if (d4.y >= lo && d4.y < hi) atomicAdd(&deg[d4.y], 1);
            if (d4.z >= lo && d4.z < hi) atomicAdd(&deg[d4.z], 1);
            if (d4.w >= lo && d4.w < hi) atomicAdd(&deg[d4.w], 1);
        } else {
            for (int k = i; k < e; ++k) {
                int d = dst[k];
                if (d >= lo && d < hi) atomicAdd(&deg[d], 1);
            }
        }
    }
}

__global__ void k_dis(const int* __restrict__ deg, float* __restrict__ dis, int n) {
    int i = blockIdx.x * 256 + threadIdx.x;
    if (i < n) dis[i] = rsqrtf((float)deg[i]);
}

__global__ void k_scanA(const int* __restrict__ deg, int* __restrict__ row_ptr,
                        int* __restrict__ blksums, int n) {
    __shared__ int s[1024];
    int tid = threadIdx.x;
    int i = blockIdx.x * 1024 + tid;
    int v = (i < n) ? (deg[i] - 1) : 0;
    s[tid] = v;
    __syncthreads();
    for (int off = 1; off < 1024; off <<= 1) {
        int t = (tid >= off) ? s[tid - off] : 0;
        __syncthreads();
        s[tid] += t;
        __syncthreads();
    }
    if (i < n) row_ptr[i] = s[tid] - v;
    if (tid == 1023) blksums[blockIdx.x] = s[1023];
}

__global__ void k_scanB(const int* __restrict__ blksums, int* __restrict__ blkoffs, int nb) {
    __shared__ int s[1024];
    int tid = threadIdx.x;
    int v = (tid < nb) ? blksums[tid] : 0;
    s[tid] = v;
    __syncthreads();
    for (int off = 1; off < 1024; off <<= 1) {
        int t = (tid >= off) ? s[tid - off] : 0;
        __syncthreads();
        s[tid] += t;
        __syncthreads();
    }
    if (tid < nb) blkoffs[tid] = s[tid] - v;
}

__global__ void k_scanC(int* __restrict__ row_ptr, const int* __restrict__ blkoffs,
                        int* __restrict__ write_ptr, int n) {
    int i = blockIdx.x * 1024 + threadIdx.x;
    if (i < n) {
        int r = row_ptr[i] + blkoffs[blockIdx.x];
        row_ptr[i] = r;
        write_ptr[i] = r;
    }
}

__global__ void k_fill_part(const int* __restrict__ src, const int* __restrict__ dst,
                            int* __restrict__ write_ptr, int* __restrict__ adj,
                            int e, int nrange, int n) {
    int g  = blockIdx.x & (NGROUP - 1);
    int lo = g * nrange;
    int hi = min(n, lo + nrange);
    int bid  = blockIdx.x >> 3;
    int nblk = gridDim.x >> 3;
    int i0   = (bid * 256 + threadIdx.x) * 4;
    int step = nblk * 256 * 4;
    for (int i = i0; i < e; i += step) {
        if (i + 4 <= e) {
            int4 d4 = *(const int4*)(dst + i);
            if (d4.x >= lo && d4.x < hi) { int slot = atomicAdd(&write_ptr[d4.x], 1); adj[slot] = src[i];     }
            if (d4.y >= lo && d4.y < hi) { int slot = atomicAdd(&write_ptr[d4.y], 1); adj[slot] = src[i + 1]; }
            if (d4.z >= lo && d4.z < hi) { int slot = atomicAdd(&write_ptr[d4.z], 1); adj[slot] = src[i + 2]; }
            if (d4.w >= lo && d4.w < hi) { int slot = atomicAdd(&write_ptr[d4.w], 1); adj[slot] = src[i + 3]; }
        } else {
            for (int k = i; k < e; ++k) {
                int d = dst[k];
                if (d >= lo && d < hi) { int slot = atomicAdd(&write_ptr[d], 1); adj[slot] = src[k]; }
            }
        }
    }
}

// ---------------- xn = x * dis, padded to 20 floats ----------------

__global__ void k_xn(const float* __restrict__ x, const float* __restrict__ dis,
                     float* __restrict__ xn, int n) {
    int gid = blockIdx.x * 256 + threadIdx.x;
    if (gid >= n * 5) return;
    int i = gid / 5, s = gid - (gid / 5) * 5;
    float dn = dis[i];
    const float* xr = x + (size_t)i * IN_DIM;
    float4 v;
    int k = s * 4;
    v.x = (k + 0 < IN_DIM) ? xr[k + 0] * dn : 0.f;
    v.y = (k + 1 < IN_DIM) ? xr[k + 1] * dn : 0.f;
    v.z = (k + 2 < IN_DIM) ? xr[k + 2] * dn : 0.f;
    v.w = (k + 3 < IN_DIM) ? xr[k + 3] * dn : 0.f;
    *(float4*)(xn + (size_t)i * XPAD + k) = v;
}

// ---------------- fused layer-1: gather xn rows + W1 + bias + relu -> h ------
// r7-proven structure (78us @ 76% occ): wave per node, 12 edge-groups x 5
// lanes x float4, x2 unroll = 24 gathers in flight; small LDS (no W2).

__global__ void k_agg1f(const float* __restrict__ xn, const int* __restrict__ row_ptr,
                        const int* __restrict__ deg, const int* __restrict__ adj,
                        const float* __restrict__ dis, const float* __restrict__ W1,
                        const float* __restrict__ b1, float* __restrict__ h, int n) {
    __shared__ float sw[IN_DIM * HID];
    __shared__ float sb[HID];
    __shared__ __align__(16) float sagg[4][XPAD];
    int tid = threadIdx.x;
    for (int t = tid; t < IN_DIM * HID; t += 256) sw[t] = W1[t];
    if (tid < HID) sb[tid] = b1[tid];
    __syncthreads();
    int node = blockIdx.x * 4 + (tid >> 6);
    if (node >= n) return;
    int lane = tid & 63;
    int wv = tid >> 6;
    int eg = lane / 5;               // 0..12 (lanes 60-63 inactive)
    int sl = lane - eg * 5;          // float4 slot 0..4
    bool act = eg < 12;
    int beg = row_ptr[node];
    int cnt = deg[node] - 1;
    const int* a = adj + beg;
    float4 acc = make_float4(0.f, 0.f, 0.f, 0.f);
    int base = 0;
    for (; base + 24 <= cnt; base += 24) {
        if (act) {
            int j0 = a[base + eg];
            int j1 = a[base + 12 + eg];
            float4 v0 = *(const float4*)(xn + (size_t)j0 * XPAD + sl * 4);
            float4 v1 = *(const float4*)(xn + (size_t)j1 * XPAD + sl * 4);
            acc.x += v0.x + v1.x; acc.y += v0.y + v1.y;
            acc.z += v0.z + v1.z; acc.w += v0.w + v1.w;
        }
    }
    if (act && base + eg < cnt) {
        float4 v = *(const float4*)(xn + (size_t)a[base + eg] * XPAD + sl * 4);
        acc.x += v.x; acc.y += v.y; acc.z += v.z; acc.w += v.w;
    }
    if (act && base + 12 + eg < cnt) {
        float4 v = *(const float4*)(xn + (size_t)a[base + 12 + eg] * XPAD + sl * 4);
        acc.x += v.x; acc.y += v.y; acc.z += v.z; acc.w += v.w;
    }
    // reduce 12 groups -> group 0
    float4 t = shfl_f4(acc, lane + 30);
    if (lane < 30) { acc.x += t.x; acc.y += t.y; acc.z += t.z; acc.w += t.w; }
    t = shfl_f4(acc, lane + 15);
    if (lane < 15) { acc.x += t.x; acc.y += t.y; acc.z += t.z; acc.w += t.w; }
    t = shfl_f4(acc, lane + 10);
    if (lane < 5) { acc.x += t.x; acc.y += t.y; acc.z += t.z; acc.w += t.w; }
    t = shfl_f4(acc, lane + 5);
    if (lane < 5) { acc.x += t.x; acc.y += t.y; acc.z += t.z; acc.w += t.w; }
    if (lane < 5) {
        float4 s4v = *(const float4*)(xn + (size_t)node * XPAD + lane * 4);
        acc.x += s4v.x; acc.y += s4v.y; acc.z += s4v.z; acc.w += s4v.w;
        *(float4*)&sagg[wv][lane * 4] = acc;   // same-wave LDS: no barrier needed
    }
    float s = 0.f;
#pragma unroll
    for (int k = 0; k < IN_DIM; ++k) s += sagg[wv][k] * sw[k * HID + lane];
    float hv = dis[node] * s + sb[lane];
    h[(size_t)node * HID + lane] = hv > 0.f ? hv : 0.f;
}

// ---------------- layer-2 GEMM (streaming, r7-proven) ----------------

__global__ void k_gemm2(const float* __restrict__ h, const float* __restrict__ W2,
                        const float* __restrict__ dis, float* __restrict__ hn2, int n) {
    __shared__ float w[HID * EMB];
    for (int t = threadIdx.x; t < HID * EMB; t += 256) w[t] = W2[t];
    __syncthreads();
    int gid = blockIdx.x * 256 + threadIdx.x;
    int i = gid >> 5, g = gid & 31;
    if (i >= n) return;
    const float* hr = h + (size_t)i * HID;
    float acc = 0.f;
#pragma unroll
    for (int k = 0; k < HID; ++k) acc += hr[k] * w[k * EMB + g];
    hn2[(size_t)i * EMB + g] = acc * dis[i];
}

// ---------------- layer-2 aggregation (float4 per lane, x3 unroll) ----------

__global__ void k_agg2(const float* __restrict__ hn2, const int* __restrict__ row_ptr,
                       const int* __restrict__ deg, const int* __restrict__ adj,
                       const float* __restrict__ dis, const float* __restrict__ b2,
                       float* __restrict__ z, int n) {
    int node = blockIdx.x * 4 + (threadIdx.x >> 6);
    if (node >= n) return;
    int lane = threadIdx.x & 63;
    int eg = lane >> 3;
    int d4 = lane & 7;
    int beg = row_ptr[node];
    int cnt = deg[node] - 1;
    const int* a = adj + beg;
    float4 acc = make_float4(0.f, 0.f, 0.f, 0.f);
    int base = 0;
    for (; base + 24 <= cnt; base += 24) {
        int j0 = a[base + eg];
        int j1 = a[base + 8 + eg];
        int j2 = a[base + 16 + eg];
        float4 v0 = *(const float4*)(hn2 + (size_t)j0 * EMB + d4 * 4);
        float4 v1 = *(const float4*)(hn2 + (size_t)j1 * EMB + d4 * 4);
        float4 v2 = *(const float4*)(hn2 + (size_t)j2 * EMB + d4 * 4);
        acc.x += v0.x + v1.x + v2.x; acc.y += v0.y + v1.y + v2.y;
        acc.z += v0.z + v1.z + v2.z; acc.w += v0.w + v1.w + v2.w;
    }
    int kk = base + eg;
    if (kk < cnt) {
        float4 v = *(const float4*)(hn2 + (size_t)a[kk] * EMB + d4 * 4);
        acc.x += v.x; acc.y += v.y; acc.z += v.z; acc.w += v.w;
    }
    kk += 8;
    if (kk < cnt) {
        float4 v = *(const float4*)(hn2 + (size_t)a[kk] * EMB + d4 * 4);
        acc.x += v.x; acc.y += v.y; acc.z += v.z; acc.w += v.w;
    }
    kk += 8;
    if (kk < cnt) {
        float4 v = *(const float4*)(hn2 + (size_t)a[kk] * EMB + d4 * 4);
        acc.x += v.x; acc.y += v.y; acc.z += v.z; acc.w += v.w;
    }
    float4 t = shfl_xor_f4(acc, 8);
    acc.x += t.x; acc.y += t.y; acc.z += t.z; acc.w += t.w;
    t = shfl_xor_f4(acc, 16);
    acc.x += t.x; acc.y += t.y; acc.z += t.z; acc.w += t.w;
    t = shfl_xor_f4(acc, 32);
    acc.x += t.x; acc.y += t.y; acc.z += t.z; acc.w += t.w;
    if (eg == 0) {
        float4 self = *(const float4*)(hn2 + (size_t)node * EMB + d4 * 4);
        float4 bb = *(const float4*)(b2 + d4 * 4);
        float dn = dis[node];
        float4 o;
        o.x = dn * (acc.x + self.x) + bb.x;
        o.y = dn * (acc.y + self.y) + bb.y;
        o.z = dn * (acc.z + self.z) + bb.z;
        o.w = dn * (acc.w + self.w) + bb.w;
        *(float4*)(z + (size_t)node * EMB + d4 * 4) = o;
    }
}

// ---------------- pair head ----------------

__global__ void k_head(const float* __restrict__ z, const int* __restrict__ tg,
                       const float* __restrict__ Wo, const float* __restrict__ bo,
                       float* __restrict__ out, int btot) {
    int i = blockIdx.x * 256 + threadIdx.x;
    if (i >= btot) return;
    int t0 = tg[i], t1 = tg[btot + i];
    const float* z0 = z + (size_t)t0 * EMB;
    const float* z1 = z + (size_t)t1 * EMB;
    float acc = 0.f;
#pragma unroll
    for (int g = 0; g < EMB; ++g) acc += z0[g] * z1[g] * Wo[g];
    out[i] = acc + bo[0];
}

// ---------------- launch ----------------

extern "C" void kernel_launch(void* const* d_in, const int* in_sizes, int n_in,
                              void* d_out, int out_size, void* d_ws, size_t ws_size,
                              hipStream_t stream) {
    const float* x  = (const float*)d_in[0];
    const int*   ei = (const int*)d_in[1];
    const int*   tg = (const int*)d_in[2];
    const float* W1 = (const float*)d_in[3];
    const float* b1 = (const float*)d_in[4];
    const float* W2 = (const float*)d_in[5];
    const float* b2 = (const float*)d_in[6];
    const float* Wo = (const float*)d_in[7];
    const float* bo = (const float*)d_in[8];
    float* out = (float*)d_out;

    int n = in_sizes[0] / IN_DIM;
    int e = in_sizes[1] / 2;
    int b = in_sizes[2] / 2;
    const int* src = ei;
    const int* dst = ei + e;

    char* ws = (char*)d_ws;
    size_t off = 0;
    auto alloc = [&](size_t bytes) -> char* {
        char* p = ws + off;
        off += (bytes + 255) & ~(size_t)255;
        return p;
    };
    int*   deg       = (int*)alloc((size_t)n * 4);
    int*   row_ptr   = (int*)alloc((size_t)n * 4);
    int*   write_ptr = (int*)alloc((size_t)n * 4);
    int*   blksums   = (int*)alloc(1024 * 4);
    int*   blkoffs   = (int*)alloc(1024 * 4);
    float* dis       = (float*)alloc((size_t)n * 4);
    int*   adj       = (int*)alloc((size_t)e * 4);
    float* xn        = (float*)alloc((size_t)n * XPAD * 4);
    float* bufH      = (float*)alloc((size_t)n * HID * 4);   // h
    float* bufA      = (float*)alloc((size_t)n * EMB * 4);   // hn2
    float* bufB      = (float*)alloc((size_t)n * EMB * 4);   // z
    int*   gcnt      = (int*)alloc(1024);

    int Pp = (n + 511) >> PSHIFT;
    int meanb = (Pp > 0) ? (e / Pp) : e;
    int cap = meanb + meanb / 16 + 1024;
    size_t bucket_bytes = (size_t)Pp * cap * 4;   // u32 pairs
    bool use_buckets = (Pp <= PMAX) && (n < (1 << 23)) &&
                       ((off + bucket_bytes + 256) <= ws_size);
    u32* gbuf = (u32*)alloc(bucket_bytes);

    int nb1024 = (n + 1023) / 1024;
    int nrange = (n + NGROUP - 1) / NGROUP;
    int nblk4 = (n + 3) / 4;

    if (use_buckets) {
        k_zero<<<1, 256, 0, stream>>>(gcnt);
        k_part<<<512, 256, 0, stream>>>(src, dst, gcnt, gbuf, e, Pp, cap);
        k_build<<<Pp, 512, 0, stream>>>(gbuf, gcnt, deg, dis, row_ptr, adj, cap, n, Pp);
    } else {
        k_init<<<(n + 255) / 256, 256, 0, stream>>>(deg, gcnt, n);
        k_count_part<<<2048, 256, 0, stream>>>(dst, deg, e, nrange, n);
        k_dis<<<(n + 255) / 256, 256, 0, stream>>>(deg, dis, n);
        k_scanA<<<nb1024, 1024, 0, stream>>>(deg, row_ptr, blksums, n);
        k_scanB<<<1, 1024, 0, stream>>>(blksums, blkoffs, nb1024);
        k_scanC<<<nb1024, 1024, 0, stream>>>(row_ptr, blkoffs, write_ptr, n);
        k_fill_part<<<2048, 256, 0, stream>>>(src, dst, write_ptr, adj, e, nrange, n);
    }

    k_xn<<<((size_t)n * 5 + 255) / 256, 256, 0, stream>>>(x, dis, xn, n);
    k_agg1f<<<nblk4, 256, 0, stream>>>(xn, row_ptr, deg, adj, dis, W1, b1, bufH, n);
    k_gemm2<<<((size_t)n * EMB + 255) / 256, 256, 0, stream>>>(bufH, W2, dis, bufA, n);
    k_agg2<<<nblk4, 256, 0, stream>>>(bufA, row_ptr, deg, adj, dis, b2, bufB, n);

    k_head<<<(b + 255) / 256, 256, 0, stream>>>(bufB, tg, Wo, bo, out, b);
}

// Round 16
// 233.265 us; speedup vs baseline: 1.2824x; 1.0770x over previous
//
#include <hip/hip_runtime.h>

#define IN_DIM 18
#define XPAD 20     // 5 float4 slots
#define HID 64
#define EMB 32
#define NGROUP 8    // legacy fallback partitioning
#define PSHIFT 9    // 512 nodes per partition
#define PMAX 200    // <=200 partitions (N<=102400)
#define BCAP 80     // k_part per-tile LDS bin capacity (u32 pairs)
#define TILE 4096
#define SCAP 16896  // k_build LDS pair-staging capacity
#define NPB 16      // nodes per block in k_agg1f

typedef int vint4 __attribute__((ext_vector_type(4)));
typedef unsigned int u32;

__device__ inline float4 shfl_f4(float4 v, int srcLane) {
    float4 r;
    r.x = __shfl(v.x, srcLane);
    r.y = __shfl(v.y, srcLane);
    r.z = __shfl(v.z, srcLane);
    r.w = __shfl(v.w, srcLane);
    return r;
}

__device__ inline float4 shfl_xor_f4(float4 v, int m) {
    v.x = __shfl_xor(v.x, m);
    v.y = __shfl_xor(v.y, m);
    v.z = __shfl_xor(v.z, m);
    v.w = __shfl_xor(v.w, m);
    return v;
}

// ---------------- init ----------------

__global__ void k_zero(int* __restrict__ gcnt) {
    gcnt[threadIdx.x] = 0;
}

__global__ void k_init(int* __restrict__ deg, int* __restrict__ gcnt, int n) {
    int i = blockIdx.x * 256 + threadIdx.x;
    if (i < n) deg[i] = 1;          // legacy path
    if (i < 256) gcnt[i] = 0;
}

// ---------------- bucketing: (dst,src) -> P dst-partition buckets ----------
// pair packed as u32: (src << 9) | (dst & 511)   [requires n < 2^23]

__global__ void k_part(const int* __restrict__ src, const int* __restrict__ dst,
                       int* __restrict__ gcnt, u32* __restrict__ gbuf,
                       int e, int Pp, int cap) {
    __shared__ u32 sbuf[PMAX][BCAP];
    __shared__ int scnt[PMAX];
    __shared__ int sbase[PMAX];
    int tid = threadIdx.x;
    int ntile = (e + TILE - 1) / TILE;
    for (int tile = blockIdx.x; tile < ntile; tile += gridDim.x) {
        for (int p = tid; p < Pp; p += 256) scnt[p] = 0;
        __syncthreads();
#pragma unroll
        for (int r = 0; r < TILE / 1024; ++r) {
            int i = tile * TILE + (r * 256 + tid) * 4;
            if (i + 4 <= e) {
                vint4 s4 = __builtin_nontemporal_load((const vint4*)(src + i));
                vint4 d4 = __builtin_nontemporal_load((const vint4*)(dst + i));
#pragma unroll
                for (int k = 0; k < 4; ++k) {
                    int d = d4[k];
                    int p = d >> PSHIFT;
                    u32 pr = ((u32)s4[k] << PSHIFT) | (u32)(d & 511);
                    int pos = atomicAdd(&scnt[p], 1);
                    if (pos < BCAP) sbuf[p][pos] = pr;
                    else {
                        int gp = atomicAdd(&gcnt[p], 1);
                        __builtin_nontemporal_store(pr, &gbuf[(size_t)p * cap + gp]);
                    }
                }
            } else if (i < e) {
                for (int k = i; k < e; ++k) {
                    int d = dst[k];
                    int p = d >> PSHIFT;
                    u32 pr = ((u32)src[k] << PSHIFT) | (u32)(d & 511);
                    int pos = atomicAdd(&scnt[p], 1);
                    if (pos < BCAP) sbuf[p][pos] = pr;
                    else {
                        int gp = atomicAdd(&gcnt[p], 1);
                        __builtin_nontemporal_store(pr, &gbuf[(size_t)p * cap + gp]);
                    }
                }
            }
        }
        __syncthreads();
        for (int p = tid; p < Pp; p += 256)
            sbase[p] = atomicAdd(&gcnt[p], min(scnt[p], BCAP));
        __syncthreads();
        int wid = tid >> 6, lane = tid & 63;
        for (int p = wid; p < Pp; p += 4) {
            int c = min(scnt[p], BCAP);
            int b = sbase[p];
            for (int k = lane; k < c; k += 64)
                __builtin_nontemporal_store(sbuf[p][k], &gbuf[(size_t)p * cap + b + k]);
        }
        __syncthreads();
    }
}

// ---------------- tiny exclusive scan of bucket counts ----------------

__global__ void k_gscan(const int* __restrict__ gcnt, int* __restrict__ gbase, int Pp) {
    __shared__ int s[256];
    int t = threadIdx.x;
    int v = (t < Pp) ? gcnt[t] : 0;
    s[t] = v;
    __syncthreads();
    for (int off = 1; off < 256; off <<= 1) {
        int u = (t >= off) ? s[t - off] : 0;
        __syncthreads();
        s[t] += u;
        __syncthreads();
    }
    if (t < Pp) gbase[t] = s[t] - v;
}

// ---------------- per-partition build: deg/dis/row_ptr/adj (512 thr) --------

__global__ void k_build(const u32* __restrict__ gbuf, const int* __restrict__ gcnt,
                        const int* __restrict__ gbase, int* __restrict__ deg,
                        float* __restrict__ dis, int* __restrict__ row_ptr,
                        int* __restrict__ adj, int cap, int n) {
    __shared__ u32 spairs[SCAP];
    __shared__ int sdeg[512];
    __shared__ int sexcl[512];
    __shared__ int swp[512];
    __shared__ int sscan[512];
    int p = blockIdx.x;
    int tid = threadIdx.x;
    int lo = p << PSHIFT;
    int nn = min(n - lo, 512);
    int cnt = gcnt[p];
    int base = gbase[p];
    const u32* buf = gbuf + (size_t)p * cap;

    sdeg[tid] = 0;
    int scap = min(cnt, SCAP);
    for (int k = tid; k < scap; k += 512)
        spairs[k] = __builtin_nontemporal_load(&buf[k]);
    __syncthreads();
    for (int k = tid; k < cnt; k += 512) {
        u32 pr = (k < SCAP) ? spairs[k] : __builtin_nontemporal_load(&buf[k]);
        atomicAdd(&sdeg[pr & 511], 1);
    }
    __syncthreads();
    int v = sdeg[tid];
    sscan[tid] = v;
    __syncthreads();
    for (int off = 1; off < 512; off <<= 1) {
        int u = (tid >= off) ? sscan[tid - off] : 0;
        __syncthreads();
        sscan[tid] += u;
        __syncthreads();
    }
    sexcl[tid] = sscan[tid] - v;
    swp[tid] = 0;
    __syncthreads();
    if (tid < nn) {
        int dg = sdeg[tid] + 1;
        deg[lo + tid] = dg;
        dis[lo + tid] = rsqrtf((float)dg);
        row_ptr[lo + tid] = base + sexcl[tid];
    }
    for (int k = tid; k < cnt; k += 512) {
        u32 pr = (k < SCAP) ? spairs[k] : __builtin_nontemporal_load(&buf[k]);
        int dl = pr & 511;
        int slot = sexcl[dl] + atomicAdd(&swp[dl], 1);
        adj[base + slot] = (int)(pr >> PSHIFT);
    }
}

// ---------------- legacy fallback ----------------

__global__ void k_count_part(const int* __restrict__ dst, int* __restrict__ deg,
                             int e, int nrange, int n) {
    int g  = blockIdx.x & (NGROUP - 1);
    int lo = g * nrange;
    int hi = min(n, lo + nrange);
    int bid  = blockIdx.x >> 3;
    int nblk = gridDim.x >> 3;
    int i0   = (bid * 256 + threadIdx.x) * 4;
    int step = nblk * 256 * 4;
    for (int i = i0; i < e; i += step) {
        if (i + 4 <= e) {
            int4 d4 = *(const int4*)(dst + i);
            if (d4.x >= lo && d4.x < hi) atomicAdd(&deg[d4.x], 1);
            if (d4.y >= lo && d4.y < hi) atomicAdd(&deg[d4.y], 1);
            if (d4.z >= lo && d4.z < hi) atomicAdd(&deg[d4.z], 1);
            if (d4.w >= lo && d4.w < hi) atomicAdd(&deg[d4.w], 1);
        } else {
            for (int k = i; k < e; ++k) {
                int d = dst[k];
                if (d >= lo && d < hi) atomicAdd(&deg[d], 1);
            }
        }
    }
}

__global__ void k_dis(const int* __restrict__ deg, float* __restrict__ dis, int n) {
    int i = blockIdx.x * 256 + threadIdx.x;
    if (i < n) dis[i] = rsqrtf((float)deg[i]);
}

__global__ void k_scanA(const int* __restrict__ deg, int* __restrict__ row_ptr,
                        int* __restrict__ blksums, int n) {
    __shared__ int s[1024];
    int tid = threadIdx.x;
    int i = blockIdx.x * 1024 + tid;
    int v = (i < n) ? (deg[i] - 1) : 0;
    s[tid] = v;
    __syncthreads();
    for (int off = 1; off < 1024; off <<= 1) {
        int t = (tid >= off) ? s[tid - off] : 0;
        __syncthreads();
        s[tid] += t;
        __syncthreads();
    }
    if (i < n) row_ptr[i] = s[tid] - v;
    if (tid == 1023) blksums[blockIdx.x] = s[1023];
}

__global__ void k_scanB(const int* __restrict__ blksums, int* __restrict__ blkoffs, int nb) {
    __shared__ int s[1024];
    int tid = threadIdx.x;
    int v = (tid < nb) ? blksums[tid] : 0;
    s[tid] = v;
    __syncthreads();
    for (int off = 1; off < 1024; off <<= 1) {
        int t = (tid >= off) ? s[tid - off] : 0;
        __syncthreads();
        s[tid] += t;
        __syncthreads();
    }
    if (tid < nb) blkoffs[tid] = s[tid] - v;
}

__global__ void k_scanC(int* __restrict__ row_ptr, const int* __restrict__ blkoffs,
                        int* __restrict__ write_ptr, int n) {
    int i = blockIdx.x * 1024 + threadIdx.x;
    if (i < n) {
        int r = row_ptr[i] + blkoffs[blockIdx.x];
        row_ptr[i] = r;
        write_ptr[i] = r;
    }
}

__global__ void k_fill_part(const int* __restrict__ src, const int* __restrict__ dst,
                            int* __restrict__ write_ptr, int* __restrict__ adj,
                            int e, int nrange, int n) {
    int g  = blockIdx.x & (NGROUP - 1);
    int lo = g * nrange;
    int hi = min(n, lo + nrange);
    int bid  = blockIdx.x >> 3;
    int nblk = gridDim.x >> 3;
    int i0   = (bid * 256 + threadIdx.x) * 4;
    int step = nblk * 256 * 4;
    for (int i = i0; i < e; i += step) {
        if (i + 4 <= e) {
            int4 d4 = *(const int4*)(dst + i);
            if (d4.x >= lo && d4.x < hi) { int slot = atomicAdd(&write_ptr[d4.x], 1); adj[slot] = src[i];     }
            if (d4.y >= lo && d4.y < hi) { int slot = atomicAdd(&write_ptr[d4.y], 1); adj[slot] = src[i + 1]; }
            if (d4.z >= lo && d4.z < hi) { int slot = atomicAdd(&write_ptr[d4.z], 1); adj[slot] = src[i + 2]; }
            if (d4.w >= lo && d4.w < hi) { int slot = atomicAdd(&write_ptr[d4.w], 1); adj[slot] = src[i + 3]; }
        } else {
            for (int k = i; k < e; ++k) {
                int d = dst[k];
                if (d >= lo && d < hi) { int slot = atomicAdd(&write_ptr[d], 1); adj[slot] = src[k]; }
            }
        }
    }
}

// ---------------- xn = x * dis, padded to 20 floats ----------------

__global__ void k_xn(const float* __restrict__ x, const float* __restrict__ dis,
                     float* __restrict__ xn, int n) {
    int gid = blockIdx.x * 256 + threadIdx.x;
    if (gid >= n * 5) return;
    int i = gid / 5, s = gid - (gid / 5) * 5;
    float dn = dis[i];
    const float* xr = x + (size_t)i * IN_DIM;
    float4 v;
    int k = s * 4;
    v.x = (k + 0 < IN_DIM) ? xr[k + 0] * dn : 0.f;
    v.y = (k + 1 < IN_DIM) ? xr[k + 1] * dn : 0.f;
    v.z = (k + 2 < IN_DIM) ? xr[k + 2] * dn : 0.f;
    v.w = (k + 3 < IN_DIM) ? xr[k + 3] * dn : 0.f;
    *(float4*)(xn + (size_t)i * XPAD + k) = v;
}

// ---------------- fused layer 1+2a: gather + W1 + relu + W2, 16 nodes/block --
// r12 champion: 4 waves x 4 sequential nodes; per-node 12 edge-groups x 5
// lanes x float4, x2 unroll = 24 gathers in flight; h stays in LDS.

__global__ void k_agg1f(const float* __restrict__ xn, const int* __restrict__ row_ptr,
                        const int* __restrict__ deg, const int* __restrict__ adj,
                        const float* __restrict__ dis, const float* __restrict__ W1,
                        const float* __restrict__ b1, const float* __restrict__ W2,
                        float* __restrict__ hn2, int n) {
    __shared__ float sw[IN_DIM * HID];
    __shared__ float sw2[HID * EMB];
    __shared__ float sb[HID];
    __shared__ __align__(16) float sagg[4][XPAD];
    __shared__ float sh[4][HID];
    int tid = threadIdx.x;
    for (int t = tid; t < IN_DIM * HID; t += 256) sw[t] = W1[t];
    for (int t = tid; t < HID * EMB; t += 256) sw2[t] = W2[t];
    if (tid < HID) sb[tid] = b1[tid];
    __syncthreads();
    int lane = tid & 63;
    int wv = tid >> 6;
    int eg = lane / 5;               // 0..12 (lanes 60-63 inactive)
    int sl = lane - eg * 5;          // float4 slot 0..4
    bool act = eg < 12;

    for (int nd = wv; nd < NPB; nd += 4) {
        int node = blockIdx.x * NPB + nd;
        if (node >= n) break;        // node uniform per wave
        int beg = row_ptr[node];
        int cnt = deg[node] - 1;
        const int* a = adj + beg;
        float4 acc = make_float4(0.f, 0.f, 0.f, 0.f);
        int base = 0;
        for (; base + 24 <= cnt; base += 24) {
            if (act) {
                int j0 = a[base + eg];
                int j1 = a[base + 12 + eg];
                float4 v0 = *(const float4*)(xn + (size_t)j0 * XPAD + sl * 4);
                float4 v1 = *(const float4*)(xn + (size_t)j1 * XPAD + sl * 4);
                acc.x += v0.x + v1.x; acc.y += v0.y + v1.y;
                acc.z += v0.z + v1.z; acc.w += v0.w + v1.w;
            }
        }
        if (act && base + eg < cnt) {
            float4 v = *(const float4*)(xn + (size_t)a[base + eg] * XPAD + sl * 4);
            acc.x += v.x; acc.y += v.y; acc.z += v.z; acc.w += v.w;
        }
        if (act && base + 12 + eg < cnt) {
            float4 v = *(const float4*)(xn + (size_t)a[base + 12 + eg] * XPAD + sl * 4);
            acc.x += v.x; acc.y += v.y; acc.z += v.z; acc.w += v.w;
        }
        // reduce 12 groups -> group 0
        float4 t = shfl_f4(acc, lane + 30);
        if (lane < 30) { acc.x += t.x; acc.y += t.y; acc.z += t.z; acc.w += t.w; }
        t = shfl_f4(acc, lane + 15);
        if (lane < 15) { acc.x += t.x; acc.y += t.y; acc.z += t.z; acc.w += t.w; }
        t = shfl_f4(acc, lane + 10);
        if (lane < 5) { acc.x += t.x; acc.y += t.y; acc.z += t.z; acc.w += t.w; }
        t = shfl_f4(acc, lane + 5);
        if (lane < 5) { acc.x += t.x; acc.y += t.y; acc.z += t.z; acc.w += t.w; }
        float dn = dis[node];
        if (lane < 5) {
            float4 s4v = *(const float4*)(xn + (size_t)node * XPAD + lane * 4);
            acc.x += s4v.x; acc.y += s4v.y; acc.z += s4v.z; acc.w += s4v.w;
            *(float4*)&sagg[wv][lane * 4] = acc;   // same-wave LDS
        }
        float s = 0.f;
#pragma unroll
        for (int k = 0; k < IN_DIM; ++k) s += sagg[wv][k] * sw[k * HID + lane];
        float hv = dn * s + sb[lane];
        sh[wv][lane] = hv > 0.f ? hv : 0.f;        // h row stays in LDS
        int g = lane & 31, half = lane >> 5;
        float s2 = 0.f;
#pragma unroll
        for (int k = 0; k < 32; ++k)
            s2 += sh[wv][half * 32 + k] * sw2[(half * 32 + k) * EMB + g];
        s2 += __shfl_xor(s2, 32);
        if (half == 0) hn2[(size_t)node * EMB + g] = dn * s2;
    }
}

// ---------------- layer-2 aggregation (float4 per lane, x3 unroll) ----------

__global__ void k_agg2(const float* __restrict__ hn2, const int* __restrict__ row_ptr,
                       const int* __restrict__ deg, const int* __restrict__ adj,
                       const float* __restrict__ dis, const float* __restrict__ b2,
                       float* __restrict__ z, int n) {
    int node = blockIdx.x * 4 + (threadIdx.x >> 6);
    if (node >= n) return;
    int lane = threadIdx.x & 63;
    int eg = lane >> 3;
    int d4 = lane & 7;
    int beg = row_ptr[node];
    int cnt = deg[node] - 1;
    const int* a = adj + beg;
    float4 acc = make_float4(0.f, 0.f, 0.f, 0.f);
    int base = 0;
    for (; base + 24 <= cnt; base += 24) {
        int j0 = a[base + eg];
        int j1 = a[base + 8 + eg];
        int j2 = a[base + 16 + eg];
        float4 v0 = *(const float4*)(hn2 + (size_t)j0 * EMB + d4 * 4);
        float4 v1 = *(const float4*)(hn2 + (size_t)j1 * EMB + d4 * 4);
        float4 v2 = *(const float4*)(hn2 + (size_t)j2 * EMB + d4 * 4);
        acc.x += v0.x + v1.x + v2.x; acc.y += v0.y + v1.y + v2.y;
        acc.z += v0.z + v1.z + v2.z; acc.w += v0.w + v1.w + v2.w;
    }
    int kk = base + eg;
    if (kk < cnt) {
        float4 v = *(const float4*)(hn2 + (size_t)a[kk] * EMB + d4 * 4);
        acc.x += v.x; acc.y += v.y; acc.z += v.z; acc.w += v.w;
    }
    kk += 8;
    if (kk < cnt) {
        float4 v = *(const float4*)(hn2 + (size_t)a[kk] * EMB + d4 * 4);
        acc.x += v.x; acc.y += v.y; acc.z += v.z; acc.w += v.w;
    }
    kk += 8;
    if (kk < cnt) {
        float4 v = *(const float4*)(hn2 + (size_t)a[kk] * EMB + d4 * 4);
        acc.x += v.x; acc.y += v.y; acc.z += v.z; acc.w += v.w;
    }
    float4 t = shfl_xor_f4(acc, 8);
    acc.x += t.x; acc.y += t.y; acc.z += t.z; acc.w += t.w;
    t = shfl_xor_f4(acc, 16);
    acc.x += t.x; acc.y += t.y; acc.z += t.z; acc.w += t.w;
    t = shfl_xor_f4(acc, 32);
    acc.x += t.x; acc.y += t.y; acc.z += t.z; acc.w += t.w;
    if (eg == 0) {
        float4 self = *(const float4*)(hn2 + (size_t)node * EMB + d4 * 4);
        float4 bb = *(const float4*)(b2 + d4 * 4);
        float dn = dis[node];
        float4 o;
        o.x = dn * (acc.x + self.x) + bb.x;
        o.y = dn * (acc.y + self.y) + bb.y;
        o.z = dn * (acc.z + self.z) + bb.z;
        o.w = dn * (acc.w + self.w) + bb.w;
        *(float4*)(z + (size_t)node * EMB + d4 * 4) = o;
    }
}

// ---------------- pair head ----------------

__global__ void k_head(const float* __restrict__ z, const int* __restrict__ tg,
                       const float* __restrict__ Wo, const float* __restrict__ bo,
                       float* __restrict__ out, int btot) {
    int i = blockIdx.x * 256 + threadIdx.x;
    if (i >= btot) return;
    int t0 = tg[i], t1 = tg[btot + i];
    const float* z0 = z + (size_t)t0 * EMB;
    const float* z1 = z + (size_t)t1 * EMB;
    float acc = 0.f;
#pragma unroll
    for (int g = 0; g < EMB; ++g) acc += z0[g] * z1[g] * Wo[g];
    out[i] = acc + bo[0];
}

// ---------------- launch ----------------

extern "C" void kernel_launch(void* const* d_in, const int* in_sizes, int n_in,
                              void* d_out, int out_size, void* d_ws, size_t ws_size,
                              hipStream_t stream) {
    const float* x  = (const float*)d_in[0];
    const int*   ei = (const int*)d_in[1];
    const int*   tg = (const int*)d_in[2];
    const float* W1 = (const float*)d_in[3];
    const float* b1 = (const float*)d_in[4];
    const float* W2 = (const float*)d_in[5];
    const float* b2 = (const float*)d_in[6];
    const float* Wo = (const float*)d_in[7];
    const float* bo = (const float*)d_in[8];
    float* out = (float*)d_out;

    int n = in_sizes[0] / IN_DIM;
    int e = in_sizes[1] / 2;
    int b = in_sizes[2] / 2;
    const int* src = ei;
    const int* dst = ei + e;

    char* ws = (char*)d_ws;
    size_t off = 0;
    auto alloc = [&](size_t bytes) -> char* {
        char* p = ws + off;
        off += (bytes + 255) & ~(size_t)255;
        return p;
    };
    int*   deg       = (int*)alloc((size_t)n * 4);
    int*   row_ptr   = (int*)alloc((size_t)n * 4);
    int*   write_ptr = (int*)alloc((size_t)n * 4);
    int*   blksums   = (int*)alloc(1024 * 4);
    int*   blkoffs   = (int*)alloc(1024 * 4);
    float* dis       = (float*)alloc((size_t)n * 4);
    int*   adj       = (int*)alloc((size_t)e * 4);
    float* xn        = (float*)alloc((size_t)n * XPAD * 4);
    float* bufA      = (float*)alloc((size_t)n * EMB * 4);   // hn2
    float* bufB      = (float*)alloc((size_t)n * EMB * 4);   // z
    int*   gcnt      = (int*)alloc(1024);
    int*   gbase     = (int*)alloc(1024);

    int Pp = (n + 511) >> PSHIFT;
    int meanb = (Pp > 0) ? (e / Pp) : e;
    int cap = meanb + meanb / 16 + 1024;
    size_t bucket_bytes = (size_t)Pp * cap * 4;   // u32 pairs
    bool use_buckets = (Pp <= PMAX) && (n < (1 << 23)) &&
                       ((off + bucket_bytes + 256) <= ws_size);
    u32* gbuf = (u32*)alloc(bucket_bytes);

    int nb1024 = (n + 1023) / 1024;
    int nrange = (n + NGROUP - 1) / NGROUP;
    int nblk4 = (n + 3) / 4;

    if (use_buckets) {
        k_zero<<<1, 256, 0, stream>>>(gcnt);
        k_part<<<512, 256, 0, stream>>>(src, dst, gcnt, gbuf, e, Pp, cap);
        k_gscan<<<1, 256, 0, stream>>>(gcnt, gbase, Pp);
        k_build<<<Pp, 512, 0, stream>>>(gbuf, gcnt, gbase, deg, dis, row_ptr, adj, cap, n);
    } else {
        k_init<<<(n + 255) / 256, 256, 0, stream>>>(deg, gcnt, n);
        k_count_part<<<2048, 256, 0, stream>>>(dst, deg, e, nrange, n);
        k_dis<<<(n + 255) / 256, 256, 0, stream>>>(deg, dis, n);
        k_scanA<<<nb1024, 1024, 0, stream>>>(deg, row_ptr, blksums, n);
        k_scanB<<<1, 1024, 0, stream>>>(blksums, blkoffs, nb1024);
        k_scanC<<<nb1024, 1024, 0, stream>>>(row_ptr, blkoffs, write_ptr, n);
        k_fill_part<<<2048, 256, 0, stream>>>(src, dst, write_ptr, adj, e, nrange, n);
    }

    k_xn<<<((size_t)n * 5 + 255) / 256, 256, 0, stream>>>(x, dis, xn, n);
    k_agg1f<<<(n + NPB - 1) / NPB, 256, 0, stream>>>(xn, row_ptr, deg, adj, dis, W1, b1, W2, bufA, n);
    k_agg2<<<nblk4, 256, 0, stream>>>(bufA, row_ptr, deg, adj, dis, b2, bufB, n);

    k_head<<<(b + 255) / 256, 256, 0, stream>>>(bufB, tg, Wo, bo, out, b);
}